// Round 8
// baseline (19973.688 us; speedup 1.0000x reference)
//
#include <hip/hip_runtime.h>
#include <stdint.h>

// ============================================================================
// ConViTCast: B=2 V=5 H=32 W=64 P=2 D=1024 NH=16 hd=64 DEPTH=2 L=512 BL=1024
// Inputs f32, output f32. Round 8: R7 + soft phase-alignment barrier in k_ode.
// R7 counters: FETCH_SIZE 21.45GB/dispatch, ~50% L2 miss — 32 drifting
// blocks/XCD thrash the exactly-L2-sized 4MB weight set. The barrier aligns
// all 256 blocks at each RK4 phase so every XCD fetches each weight line
// once and 32 blocks hit it. Timing-only: bounded spin, no deadlock, no
// coherence dependency (correctness identical to R7 which passed).
// ============================================================================

#define NSTEPS 10
#define RESF 0.01f
#define EPSF 1e-5f

typedef unsigned short u16;
typedef __attribute__((ext_vector_type(8))) short bf16x8;
typedef __attribute__((ext_vector_type(4))) float f32x4;

__device__ __forceinline__ float b2f(u16 u) {
  return __uint_as_float(((uint32_t)u) << 16);
}
__device__ __forceinline__ u16 f2b(float f) {
  uint32_t x = __float_as_uint(f);
  uint32_t r = x + 0x7fffu + ((x >> 16) & 1u);  // round-to-nearest-even
  return (u16)(r >> 16);
}
__device__ __forceinline__ float red16(float v) {
  v += __shfl_xor(v, 1); v += __shfl_xor(v, 2);
  v += __shfl_xor(v, 4); v += __shfl_xor(v, 8);
  return v;
}

// f32 -> bf16 conversion (for ODE weights)
__global__ __launch_bounds__(256) void k_cvt(
    const float* __restrict__ in, u16* __restrict__ out16, int n) {
  int i = blockIdx.x * 256 + threadIdx.x;
  if (i < n) out16[i] = f2b(in[i]);
}

// zero the soft-barrier counter (ws is poisoned 0xAA before every launch)
__global__ void k_zero(unsigned* __restrict__ p) { *p = 0u; }

// ---------------------------------------------------------------------------
// Extract patches[m*20 + v*4 + p] from x[b,v,h,w]; m=b*512+l, l=hh*32+ww
// ---------------------------------------------------------------------------
__global__ __launch_bounds__(256) void k_patches(
    const float* __restrict__ x, float* __restrict__ patches) {
  int i = blockIdx.x * 256 + threadIdx.x;  // grid 80*256 = 20480
  int m = i / 20, r = i % 20;
  int v = r >> 2, p = r & 3;
  int b = m >> 9, l = m & 511;
  int hh = l >> 5, ww = l & 31;
  int pr = p >> 1, pc = p & 1;
  patches[i] = x[((size_t)(b * 5 + v) * 32 + hh * 2 + pr) * 64 + ww * 2 + pc];
}

// qvec = var_query @ Wq^T + bq   (grid 64)
__global__ __launch_bounds__(256) void k_qvec(
    const float* __restrict__ vq, const float* __restrict__ w,
    const float* __restrict__ bias, float* __restrict__ qvec) {
  int dq = blockIdx.x * 16 + (threadIdx.x >> 4);
  int lane = threadIdx.x & 15;
  float p = 0.f;
  for (int j = 0; j < 64; j++) {
    int d = lane + 16 * j;
    p += vq[d] * w[(size_t)dq * 1024 + d];
  }
  p = red16(p);
  if (lane == 0) qvec[dq] = p + bias[dq];
}

// qb[h] = sum_e qvec[h*64+e]*bk[h*64+e]   (grid 1)
__global__ __launch_bounds__(256) void k_qb(
    const float* __restrict__ qvec, const float* __restrict__ bk,
    float* __restrict__ qb) {
  int h = threadIdx.x >> 4, lane = threadIdx.x & 15;
  float p = 0.f;
  for (int e = lane; e < 64; e += 16) p += qvec[h * 64 + e] * bk[h * 64 + e];
  p = red16(p);
  if (lane == 0) qb[h] = p;
}

// u[h][d] = sum_e qvec[h*64+e] * Wk[h*64+e][d]   (grid 64)
__global__ __launch_bounds__(256) void k_u(
    const float* __restrict__ qvec, const float* __restrict__ wk,
    float* __restrict__ u) {
  int d = blockIdx.x * 16 + (threadIdx.x & 15);
  int h = threadIdx.x >> 4;
  float acc = 0.f;
  for (int e = 0; e < 64; e++)
    acc += qvec[h * 64 + e] * wk[(size_t)(h * 64 + e) * 1024 + d];
  u[h * 1024 + d] = acc;
}

// PU[(v*16+h)*4+p] = 0.125*sum_d pw[v,d,p]*u[h,d]
// C0[v*16+h]       = 0.125*(sum_d (pb+ve)[v,d]*u[h,d] + qb[h])     (grid 80)
__global__ __launch_bounds__(256) void k_pu(
    const float* __restrict__ pw, const float* __restrict__ pb,
    const float* __restrict__ ve, const float* __restrict__ u,
    const float* __restrict__ qb, float* __restrict__ PU,
    float* __restrict__ C0) {
  int v = blockIdx.x / 16, h = blockIdx.x % 16;
  int t = threadIdx.x;
  float a0 = 0, a1 = 0, a2 = 0, a3 = 0, ac = 0;
  for (int d = t; d < 1024; d += 256) {
    float uu = u[h * 1024 + d];
    const float* p4 = pw + ((size_t)v * 1024 + d) * 4;
    a0 += p4[0] * uu; a1 += p4[1] * uu; a2 += p4[2] * uu; a3 += p4[3] * uu;
    ac += (pb[v * 1024 + d] + ve[v * 1024 + d]) * uu;
  }
  for (int off = 1; off < 64; off <<= 1) {
    a0 += __shfl_xor(a0, off); a1 += __shfl_xor(a1, off);
    a2 += __shfl_xor(a2, off); a3 += __shfl_xor(a3, off);
    ac += __shfl_xor(ac, off);
  }
  __shared__ float r[4][5];
  if ((t & 63) == 0) {
    int w = t >> 6;
    r[w][0] = a0; r[w][1] = a1; r[w][2] = a2; r[w][3] = a3; r[w][4] = ac;
  }
  __syncthreads();
  if (t == 0) {
    float s[5];
    for (int j = 0; j < 5; j++) s[j] = r[0][j] + r[1][j] + r[2][j] + r[3][j];
    float* pu = PU + (v * 16 + h) * 4;
    pu[0] = 0.125f * s[0]; pu[1] = 0.125f * s[1];
    pu[2] = 0.125f * s[2]; pu[3] = 0.125f * s[3];
    C0[v * 16 + h] = 0.125f * (s[4] + qb[h]);
  }
}

// PW[(v*1024+col)*4+p] = sum_d Wv[col,d]*pw[v,d,p]
// CV[v*1024+col]       = sum_d Wv[col,d]*(pb+ve)[v,d] + bv[col]    (grid 5120)
__global__ __launch_bounds__(256) void k_pw(
    const float* __restrict__ wv, const float* __restrict__ bv,
    const float* __restrict__ pw, const float* __restrict__ pb,
    const float* __restrict__ ve, float* __restrict__ PW,
    float* __restrict__ CV) {
  int v = blockIdx.x >> 10, col = blockIdx.x & 1023;
  int t = threadIdx.x;
  const float* wr = wv + (size_t)col * 1024;
  float4 w4 = *(const float4*)(wr + t * 4);
  float a0 = 0, a1 = 0, a2 = 0, a3 = 0, ac = 0;
#pragma unroll
  for (int j = 0; j < 4; j++) {
    int d = t * 4 + j;
    float wj = (j == 0) ? w4.x : (j == 1) ? w4.y : (j == 2) ? w4.z : w4.w;
    const float* p4 = pw + ((size_t)v * 1024 + d) * 4;
    a0 += wj * p4[0]; a1 += wj * p4[1]; a2 += wj * p4[2]; a3 += wj * p4[3];
    ac += wj * (pb[v * 1024 + d] + ve[v * 1024 + d]);
  }
  for (int off = 1; off < 64; off <<= 1) {
    a0 += __shfl_xor(a0, off); a1 += __shfl_xor(a1, off);
    a2 += __shfl_xor(a2, off); a3 += __shfl_xor(a3, off);
    ac += __shfl_xor(ac, off);
  }
  __shared__ float r[4][5];
  if ((t & 63) == 0) {
    int w = t >> 6;
    r[w][0] = a0; r[w][1] = a1; r[w][2] = a2; r[w][3] = a3; r[w][4] = ac;
  }
  __syncthreads();
  if (t == 0) {
    float s[5];
    for (int j = 0; j < 5; j++) s[j] = r[0][j] + r[1][j] + r[2][j] + r[3][j];
    float* o = PW + ((size_t)(v * 1024 + col)) * 4;
    o[0] = s[0]; o[1] = s[1]; o[2] = s[2]; o[3] = s[3];
    CV[v * 1024 + col] = s[4] + bv[col];
  }
}

// scores s[v][h] = patches[m,v]·PU[v,h] + C0[v,h]; softmax over v
// -> amat[m*80 + h*5 + v]                                          (grid 1024)
__global__ __launch_bounds__(256) void k_scoresm(
    const float* __restrict__ patches, const float* __restrict__ PU,
    const float* __restrict__ C0, float* __restrict__ amat) {
  __shared__ float pat[20];
  __shared__ float sa[16][8];
  int m = blockIdx.x, t = threadIdx.x;
  if (t < 20) pat[t] = patches[m * 20 + t];
  __syncthreads();
  if (t < 80) {
    int v = t / 16, h = t % 16;
    const float* pu = PU + (v * 16 + h) * 4;
    float s = C0[v * 16 + h] + pat[v * 4 + 0] * pu[0] + pat[v * 4 + 1] * pu[1]
            + pat[v * 4 + 2] * pu[2] + pat[v * 4 + 3] * pu[3];
    sa[h][v] = s;
  }
  __syncthreads();
  if (t < 16) {
    float mx = sa[t][0];
    for (int v = 1; v < 5; v++) mx = fmaxf(mx, sa[t][v]);
    float e[5], sum = 0.f;
    for (int v = 0; v < 5; v++) { e[v] = __expf(sa[t][v] - mx); sum += e[v]; }
    float inv = 1.f / sum;
    for (int v = 0; v < 5; v++) amat[m * 80 + t * 5 + v] = e[v] * inv;
  }
}

// agg[m,c] = sum_v amat[m,h(c),v] * (patches[m,v]·PW[v,c] + CV[v,c]) (grid 1024)
__global__ __launch_bounds__(256) void k_agg(
    const float* __restrict__ patches, const float* __restrict__ PW,
    const float* __restrict__ CV, const float* __restrict__ amat,
    float* __restrict__ agg) {
  __shared__ float pat[20];
  __shared__ float am[80];
  int m = blockIdx.x, t = threadIdx.x;
  if (t < 20) pat[t] = patches[m * 20 + t];
  if (t < 80) am[t] = amat[m * 80 + t];
  __syncthreads();
  int c0 = t * 4;
#pragma unroll
  for (int j = 0; j < 4; j++) {
    int c = c0 + j;
    int h = c >> 6;
    float acc = 0.f;
#pragma unroll
    for (int v = 0; v < 5; v++) {
      float4 w4 = *(const float4*)(PW + ((size_t)(v * 1024 + c)) * 4);
      float val = pat[v * 4 + 0] * w4.x + pat[v * 4 + 1] * w4.y
                + pat[v * 4 + 2] * w4.z + pat[v * 4 + 3] * w4.w
                + CV[v * 1024 + c];
      acc += am[h * 5 + v] * val;
    }
    agg[(size_t)m * 1024 + c] = acc;
  }
}

// ---------------------------------------------------------------------------
// Generic fp32 GEMM: C[M][N] = A[M][K] @ W[N][K]^T + bias, epilogues.
// EPI: 0 plain, 1 gelu(exact), 2 +resid, 3 +pos+lt
// ---------------------------------------------------------------------------
template <int EPI>
__global__ __launch_bounds__(256) void k_gemm(
    const float* __restrict__ A, const float* __restrict__ W,
    const float* __restrict__ bias, float* __restrict__ C,
    int M, int N, int K,
    const float* __restrict__ resid,
    const float* __restrict__ pos, const float* __restrict__ ltw,
    const float* __restrict__ ltb, const float* __restrict__ lead) {
  __shared__ float As[16][68];
  __shared__ float Ws[16][68];
  int m0 = blockIdx.y * 64, n0 = blockIdx.x * 64;
  int tid = threadIdx.x;
  int tx = tid & 15, ty = tid >> 4;
  int lr = tid & 63, lk = (tid >> 6) * 4;
  float acc[4][4] = {};
  for (int k0 = 0; k0 < K; k0 += 16) {
    float4 av = *(const float4*)(A + (size_t)(m0 + lr) * K + k0 + lk);
    float4 wv = {0.f, 0.f, 0.f, 0.f};
    if (n0 + lr < N) {
      wv = *(const float4*)(W + (size_t)(n0 + lr) * K + k0 + lk);
    }
    __syncthreads();
    As[lk + 0][lr] = av.x; As[lk + 1][lr] = av.y;
    As[lk + 2][lr] = av.z; As[lk + 3][lr] = av.w;
    Ws[lk + 0][lr] = wv.x; Ws[lk + 1][lr] = wv.y;
    Ws[lk + 2][lr] = wv.z; Ws[lk + 3][lr] = wv.w;
    __syncthreads();
#pragma unroll
    for (int kk = 0; kk < 16; kk++) {
      float4 a = *(const float4*)&As[kk][ty * 4];
      float4 b = *(const float4*)&Ws[kk][tx * 4];
      acc[0][0] += a.x * b.x; acc[0][1] += a.x * b.y; acc[0][2] += a.x * b.z; acc[0][3] += a.x * b.w;
      acc[1][0] += a.y * b.x; acc[1][1] += a.y * b.y; acc[1][2] += a.y * b.z; acc[1][3] += a.y * b.w;
      acc[2][0] += a.z * b.x; acc[2][1] += a.z * b.y; acc[2][2] += a.z * b.z; acc[2][3] += a.z * b.w;
      acc[3][0] += a.w * b.x; acc[3][1] += a.w * b.y; acc[3][2] += a.w * b.z; acc[3][3] += a.w * b.w;
    }
  }
#pragma unroll
  for (int ii = 0; ii < 4; ii++) {
    int m = m0 + ty * 4 + ii;
#pragma unroll
    for (int jj = 0; jj < 4; jj++) {
      int n = n0 + tx * 4 + jj;
      if (n >= N) continue;
      float v = acc[ii][jj] + bias[n];
      if (EPI == 1) v = 0.5f * v * (1.f + erff(v * 0.70710678118f));
      if (EPI == 2) v += resid[(size_t)m * N + n];
      if (EPI == 3) {
        int b = m >> 9, l = m & 511;
        v += pos[(size_t)l * 1024 + n] + ltw[n] * lead[b] + ltb[n];
      }
      C[(size_t)m * N + n] = v;
    }
  }
}

// ---------------------------------------------------------------------------
// LayerNorm over D=1024 (grid M). In-place safe.
// ---------------------------------------------------------------------------
__global__ __launch_bounds__(256) void k_ln(
    const float* __restrict__ src, const float* __restrict__ add,
    const float* __restrict__ g, const float* __restrict__ bb,
    float* __restrict__ dst) {
  __shared__ float red[8];
  int m = blockIdx.x, tid = threadIdx.x;
  float4 x = *(const float4*)(src + (size_t)m * 1024 + tid * 4);
  if (add) {
    float4 a2 = *(const float4*)(add + (size_t)m * 1024 + tid * 4);
    x.x += a2.x; x.y += a2.y; x.z += a2.z; x.w += a2.w;
  }
  float s1 = x.x + x.y + x.z + x.w;
  float s2 = x.x * x.x + x.y * x.y + x.z * x.z + x.w * x.w;
  for (int off = 1; off < 64; off <<= 1) {
    s1 += __shfl_xor(s1, off); s2 += __shfl_xor(s2, off);
  }
  if ((tid & 63) == 0) { red[(tid >> 6) * 2] = s1; red[(tid >> 6) * 2 + 1] = s2; }
  __syncthreads();
  s1 = red[0] + red[2] + red[4] + red[6];
  s2 = red[1] + red[3] + red[5] + red[7];
  float mean = s1 * (1.f / 1024.f);
  float var = s2 * (1.f / 1024.f) - mean * mean;
  float rstd = rsqrtf(var + EPSF);
  int c = tid * 4;
  float4 o;
  o.x = (x.x - mean) * rstd * g[c + 0] + bb[c + 0];
  o.y = (x.y - mean) * rstd * g[c + 1] + bb[c + 1];
  o.z = (x.z - mean) * rstd * g[c + 2] + bb[c + 2];
  o.w = (x.w - mean) * rstd * g[c + 3] + bb[c + 3];
  *(float4*)(dst + (size_t)m * 1024 + c) = o;
}

// ---------------------------------------------------------------------------
// Patch attention: per (b,h,ntile16). Two-pass softmax with S in LDS.
// ---------------------------------------------------------------------------
__global__ __launch_bounds__(256) void k_attn(
    const float* __restrict__ qkv, float* __restrict__ o) {
  __shared__ float Q[16][68];
  __shared__ float S[16][516];
  __shared__ float KV[32][68];
  int bid = blockIdx.x;
  int nt = bid & 31, h = (bid >> 5) & 15, b = bid >> 9;
  int tid = threadIdx.x;
  for (int i = tid; i < 16 * 64; i += 256) {
    int r = i >> 6, e = i & 63;
    Q[r][e] = qkv[(size_t)(b * 512 + nt * 16 + r) * 3072 + h * 64 + e];
  }
  __syncthreads();
  int r = tid >> 4, lane = tid & 15;
  for (int kt = 0; kt < 16; kt++) {
    for (int i = tid; i < 32 * 64; i += 256) {
      int rr = i >> 6, e = i & 63;
      KV[rr][e] = qkv[(size_t)(b * 512 + kt * 32 + rr) * 3072 + 1024 + h * 64 + e];
    }
    __syncthreads();
    for (int jj = lane; jj < 32; jj += 16) {
      float acc = 0.f;
#pragma unroll 8
      for (int e = 0; e < 64; e++) acc += Q[r][e] * KV[jj][e];
      S[r][kt * 32 + jj] = acc * 0.125f;
    }
    __syncthreads();
  }
  float mx = -1e30f;
  for (int j = lane; j < 512; j += 16) mx = fmaxf(mx, S[r][j]);
  for (int off = 1; off < 16; off <<= 1) mx = fmaxf(mx, __shfl_xor(mx, off));
  float sum = 0.f;
  for (int j = lane; j < 512; j += 16) {
    float e = __expf(S[r][j] - mx);
    S[r][j] = e; sum += e;
  }
  sum = red16(sum);
  float inv = 1.f / sum;
  int e0 = lane * 4;
  float4 accv = {0.f, 0.f, 0.f, 0.f};
  for (int kt = 0; kt < 16; kt++) {
    __syncthreads();
    for (int i = tid; i < 32 * 64; i += 256) {
      int rr = i >> 6, e = i & 63;
      KV[rr][e] = qkv[(size_t)(b * 512 + kt * 32 + rr) * 3072 + 2048 + h * 64 + e];
    }
    __syncthreads();
#pragma unroll 8
    for (int j = 0; j < 32; j++) {
      float p = S[r][kt * 32 + j] * inv;
      accv.x += p * KV[j][e0 + 0]; accv.y += p * KV[j][e0 + 1];
      accv.z += p * KV[j][e0 + 2]; accv.w += p * KV[j][e0 + 3];
    }
  }
  float* op = o + (size_t)(b * 512 + nt * 16 + r) * 1024 + h * 64 + e0;
  op[0] = accv.x; op[1] = accv.y; op[2] = accv.z; op[3] = accv.w;
}

// ---------------------------------------------------------------------------
// ODE persistent kernel v4 = v3 + soft phase-alignment barrier.
// 256 blocks x 1024 thr; block owns 4 tokens; Y/R in LDS; M=4 in 16-row tile.
// Barrier: atomicAdd + bounded spin (timing-only; timeout -> proceed).
// ---------------------------------------------------------------------------
__device__ __forceinline__ int swz(int m, int c) {
  int g = c >> 3;
  g = (g & ~7) | ((g ^ m) & 7);
  return m * 1024 + g * 8 + (c & 7);
}
__device__ __forceinline__ int swz8(int m, int k) {  // k multiple of 8
  int g = k >> 3;
  g = (g & ~7) | ((g ^ m) & 7);
  return m * 1024 + g * 8;
}

__global__ __launch_bounds__(1024, 4) void k_ode(
    const float* __restrict__ xs, float* __restrict__ out,
    const u16* __restrict__ w1, const float* __restrict__ b1,
    const u16* __restrict__ w2, const float* __restrict__ b2,
    const float* __restrict__ ng, const float* __restrict__ nb,
    const float* __restrict__ lead, unsigned* __restrict__ barrier_ctr) {
  __shared__ u16 bufA[16 * 1024];
  __shared__ u16 bufH[16 * 1024];
  __shared__ float Ys[4][1024];
  __shared__ float Rs[4][1024];
  __shared__ float redb[4][8];
  int tid = threadIdx.x;
  int m0 = blockIdx.x * 4;                 // 4 tokens per block
  int idxb = (int)roundf(lead[m0 >> 9] * 100.0f);
  int wvid = tid >> 6;                     // 0..15
  int lane = tid & 63;
  int col = lane & 15, quad = lane >> 4;
  int cbase = wvid * 64 + col;             // wave's col for tile ct: cbase+ct*16
  int tk = tid >> 8;                       // epilogue token 0..3
  int lw = wvid & 3;                       // wave-within-token
  int ch0 = (tid & 255) * 4;               // epilogue channels
  // ---- init ----
  {
    const float* yp = xs + (size_t)(m0 + tk) * 1024 + ch0;
    float* op = out + (size_t)(m0 + tk) * 1024 + ch0;
#pragma unroll
    for (int j = 0; j < 4; j++) {
      float v = yp[j];
      Ys[tk][ch0 + j] = v; op[j] = v;
      bufA[swz(tk, ch0 + j)] = f2b(v);
    }
    for (int i = tid; i < 12 * 1024; i += 1024) {  // zero A rows 4..15
      int r = 4 + (i >> 10), c = i & 1023;
      bufA[swz(r, c)] = 0;
    }
  }
  __syncthreads();
  const float h6 = RESF / 6.0f;

  for (int s = 0; s < NSTEPS; s++) {
    for (int ph = 0; ph < 4; ph++) {
      // ---- soft phase-alignment barrier (timing-only) ----
      {
        unsigned bidx = (unsigned)(s * 4 + ph);
        if (tid == 0) {
          __hip_atomic_fetch_add(barrier_ctr, 1u, __ATOMIC_RELAXED,
                                 __HIP_MEMORY_SCOPE_AGENT);
          unsigned target = (bidx + 1u) * 256u;
          long long t0 = clock64();
          while (__hip_atomic_load(barrier_ctr, __ATOMIC_RELAXED,
                                   __HIP_MEMORY_SCOPE_AGENT) < target) {
            if (clock64() - t0 > 200000LL) break;  // ~80us guard
            __builtin_amdgcn_s_sleep(4);
          }
        }
        __syncthreads();
      }
      // ---- GEMM1: h = relu(bufA @ w1^T + b1) -> bufH ----
      {
        f32x4 acc[4] = {};
        const u16* wp[4];
        bf16x8 bc[4];
#pragma unroll
        for (int ct = 0; ct < 4; ct++) {
          wp[ct] = w1 + (size_t)(cbase + ct * 16) * 1024 + quad * 8;
          bc[ct] = *(const bf16x8*)wp[ct];
        }
#pragma unroll
        for (int kc = 0; kc < 32; kc++) {
          bf16x8 bn[4];
          if (kc < 31) {
#pragma unroll
            for (int ct = 0; ct < 4; ct++)
              bn[ct] = *(const bf16x8*)(wp[ct] + (kc + 1) * 32);
          }
          bf16x8 aF = *(const bf16x8*)(bufA + swz8(col, kc * 32 + quad * 8));
#pragma unroll
          for (int ct = 0; ct < 4; ct++)
            acc[ct] = __builtin_amdgcn_mfma_f32_16x16x32_bf16(aF, bc[ct], acc[ct], 0, 0, 0);
          if (kc < 31) {
#pragma unroll
            for (int ct = 0; ct < 4; ct++) bc[ct] = bn[ct];
          }
        }
#pragma unroll
        for (int ct = 0; ct < 4; ct++) {
          int c = cbase + ct * 16;
          float bv = b1[c];
#pragma unroll
          for (int rr = 0; rr < 4; rr++)
            bufH[swz(quad * 4 + rr, c)] = f2b(fmaxf(acc[ct][rr] + bv, 0.f));
        }
      }
      __syncthreads();
      // ---- GEMM2: z = bufH @ w2^T ----
      f32x4 acc2[4] = {};
      {
        const u16* wp[4];
        bf16x8 bc[4];
#pragma unroll
        for (int ct = 0; ct < 4; ct++) {
          wp[ct] = w2 + (size_t)(cbase + ct * 16) * 1024 + quad * 8;
          bc[ct] = *(const bf16x8*)wp[ct];
        }
#pragma unroll
        for (int kc = 0; kc < 32; kc++) {
          bf16x8 bn[4];
          if (kc < 31) {
#pragma unroll
            for (int ct = 0; ct < 4; ct++)
              bn[ct] = *(const bf16x8*)(wp[ct] + (kc + 1) * 32);
          }
          bf16x8 aF = *(const bf16x8*)(bufH + swz8(col, kc * 32 + quad * 8));
#pragma unroll
          for (int ct = 0; ct < 4; ct++)
            acc2[ct] = __builtin_amdgcn_mfma_f32_16x16x32_bf16(aF, bc[ct], acc2[ct], 0, 0, 0);
          if (kc < 31) {
#pragma unroll
            for (int ct = 0; ct < 4; ct++) bc[ct] = bn[ct];
          }
        }
      }
      __syncthreads();  // all waves done READING bufH before overwrite
      // ---- z = acc2 + b2 + resid(bufA rows 0-3) -> bufH rows 0-3 ----
      if (quad == 0) {
#pragma unroll
        for (int ct = 0; ct < 4; ct++) {
          int c = cbase + ct * 16;
          float bv = b2[c];
#pragma unroll
          for (int rr = 0; rr < 4; rr++) {
            float z = acc2[ct][rr] + bv + b2f(bufA[swz(rr, c)]);
            bufH[swz(rr, c)] = f2b(z);
          }
        }
      }
      __syncthreads();
      // ---- epilogue: LN + RK4 state update ----
      {
        float z4[4];
#pragma unroll
        for (int j = 0; j < 4; j++) z4[j] = b2f(bufH[swz(tk, ch0 + j)]);
        float s1 = z4[0] + z4[1] + z4[2] + z4[3];
        float s2 = z4[0] * z4[0] + z4[1] * z4[1] + z4[2] * z4[2] + z4[3] * z4[3];
        for (int off = 1; off < 64; off <<= 1) {
          s1 += __shfl_xor(s1, off); s2 += __shfl_xor(s2, off);
        }
        if (lane == 0) { redb[tk][lw * 2] = s1; redb[tk][lw * 2 + 1] = s2; }
        __syncthreads();
        s1 = redb[tk][0] + redb[tk][2] + redb[tk][4] + redb[tk][6];
        s2 = redb[tk][1] + redb[tk][3] + redb[tk][5] + redb[tk][7];
        float mean = s1 * (1.f / 1024.f);
        float var = s2 * (1.f / 1024.f) - mean * mean;
        float rstd = rsqrtf(var + EPSF);
        float cf = (ph < 2) ? 0.5f * RESF : RESF;
        float ynew[4];
#pragma unroll
        for (int j = 0; j < 4; j++) {
          int c = ch0 + j;
          float k = (z4[j] - mean) * rstd * ng[c] + nb[c];
          float yv = Ys[tk][c];
          float nv;
          if (ph == 0)      { Rs[tk][c] = k;        nv = yv + cf * k; }
          else if (ph < 3)  { Rs[tk][c] += 2.f * k; nv = yv + cf * k; }
          else { float yn = yv + h6 * (Rs[tk][c] + k); Ys[tk][c] = yn; ynew[j] = yn; nv = yn; }
          bufA[swz(tk, c)] = f2b(nv);
        }
        if (ph == 3 && (s + 1) == idxb) {
          float* op = out + (size_t)(m0 + tk) * 1024 + ch0;
#pragma unroll
          for (int j = 0; j < 4; j++) op[j] = ynew[j];
        }
      }
      __syncthreads();
    }
  }
}

// ---------------------------------------------------------------------------
// Unpatchify: y3[m][p*10+q*5+c] -> out[b][c][hh*2+p][ww*2+q], FLOAT32
// ---------------------------------------------------------------------------
__global__ __launch_bounds__(256) void k_unpatch(
    const float* __restrict__ y3, float* __restrict__ outp) {
  int o = blockIdx.x * 256 + threadIdx.x;
  if (o >= 20480) return;
  int b = o / 10240;
  int c = (o / 2048) % 5;
  int hrow = (o / 64) % 32;
  int wcol = o % 64;
  int hh = hrow >> 1, p = hrow & 1, ww = wcol >> 1, q = wcol & 1;
  int m2 = b * 512 + hh * 32 + ww;
  int colj = p * 10 + q * 5 + c;
  outp[o] = y3[(size_t)m2 * 20 + colj];
}

// ===========================================================================
extern "C" void kernel_launch(void* const* d_in, const int* in_sizes, int n_in,
                              void* d_out, int out_size, void* d_ws, size_t ws_size,
                              hipStream_t stream) {
  const float* x         = (const float*)d_in[0];
  const float* lead      = (const float*)d_in[1];
  const float* patch_w   = (const float*)d_in[2];
  const float* patch_b   = (const float*)d_in[3];
  const float* var_embed = (const float*)d_in[4];
  const float* var_query = (const float*)d_in[5];
  const float* agg_in_w  = (const float*)d_in[6];
  const float* agg_in_b  = (const float*)d_in[7];
  const float* agg_out_w = (const float*)d_in[8];
  const float* agg_out_b = (const float*)d_in[9];
  const float* pos_embed = (const float*)d_in[10];
  const float* lt_w      = (const float*)d_in[11];
  const float* lt_b      = (const float*)d_in[12];
  const float* blk_qkv_w = (const float*)d_in[13];
  const float* blk_qkv_b = (const float*)d_in[14];
  const float* blk_out_w = (const float*)d_in[15];
  const float* blk_out_b = (const float*)d_in[16];
  const float* blk_n1_g  = (const float*)d_in[17];
  const float* blk_n1_b  = (const float*)d_in[18];
  const float* blk_n2_g  = (const float*)d_in[19];
  const float* blk_n2_b  = (const float*)d_in[20];
  const float* ode_w1    = (const float*)d_in[21];
  const float* ode_b1    = (const float*)d_in[22];
  const float* ode_w2    = (const float*)d_in[23];
  const float* ode_b2    = (const float*)d_in[24];
  const float* ode_ng    = (const float*)d_in[25];
  const float* ode_nb    = (const float*)d_in[26];
  const float* norm_g    = (const float*)d_in[27];
  const float* norm_b    = (const float*)d_in[28];
  const float* h1_w      = (const float*)d_in[29];
  const float* h1_b      = (const float*)d_in[30];
  const float* h2_w      = (const float*)d_in[31];
  const float* h2_b      = (const float*)d_in[32];
  const float* hf_w      = (const float*)d_in[33];
  const float* hf_b      = (const float*)d_in[34];
  (void)in_sizes; (void)n_in; (void)out_size; (void)ws_size;

  float* ws = (float*)d_ws;
  float* patches = ws + 0;         // 20480
  float* qvec    = ws + 20480;     // 1024
  float* qb      = ws + 21504;     // 256 (16 used)
  float* u       = ws + 21760;     // 16384
  float* PU      = ws + 38144;     // 320
  float* C0      = ws + 38464;     // 80 (pad to 40960)
  float* amat    = ws + 40960;     // 81920
  float* PW      = ws + 122880;    // 20480
  float* CV      = ws + 143360;    // 5120  (end 148480 < 3145728)
  float* agg     = ws + 3145728;   // 1048576 (attno slot; dead by then)
  float* qkv   = ws + 0;           // 3145728
  float* attno = ws + 3145728;     // 1048576
  float* t1    = ws + 4194304;     // 1048576
  float* odeo  = ws + 5242880;     // 1048576
  float* xs    = ws + 6291456;     // 1048576
  u16*   w16a  = (u16*)(ws + 7340032);  // per-depth w1 (bf16)
  u16*   w16b  = (u16*)(ws + 7864320);  // per-depth w2 (bf16)
  unsigned* bctr = (unsigned*)(ws + 8388608);  // soft-barrier counter
  float* y1 = ws + 0;
  float* y2 = ws + 1048576;
  float* y3 = ws + 2097152;        // 20480

  // ---- stage 1 ----
  k_patches<<<dim3(80), dim3(256), 0, stream>>>(x, patches);
  k_qvec<<<dim3(64), dim3(256), 0, stream>>>(var_query, agg_in_w, agg_in_b, qvec);
  k_qb<<<dim3(1), dim3(256), 0, stream>>>(qvec, agg_in_b + 1024, qb);
  k_u<<<dim3(64), dim3(256), 0, stream>>>(qvec, agg_in_w + (size_t)1024 * 1024, u);
  k_pu<<<dim3(80), dim3(256), 0, stream>>>(patch_w, patch_b, var_embed, u, qb, PU, C0);
  k_pw<<<dim3(5120), dim3(256), 0, stream>>>(
      agg_in_w + (size_t)2048 * 1024, agg_in_b + 2048, patch_w, patch_b,
      var_embed, PW, CV);
  k_scoresm<<<dim3(1024), dim3(256), 0, stream>>>(patches, PU, C0, amat);
  k_agg<<<dim3(1024), dim3(256), 0, stream>>>(patches, PW, CV, amat, agg);
  k_gemm<3><<<dim3(16, 16), dim3(256), 0, stream>>>(
      agg, agg_out_w, agg_out_b, xs, 1024, 1024, 1024,
      nullptr, pos_embed, lt_w, lt_b, lead);

  // ---- transformer blocks ----
  for (int i = 0; i < 2; i++) {
    k_gemm<0><<<dim3(48, 16), dim3(256), 0, stream>>>(
        xs, blk_qkv_w + (size_t)i * 3072 * 1024, blk_qkv_b + i * 3072, qkv,
        1024, 3072, 1024, nullptr, nullptr, nullptr, nullptr, nullptr);
    k_attn<<<dim3(1024), dim3(256), 0, stream>>>(qkv, attno);
    k_gemm<2><<<dim3(16, 16), dim3(256), 0, stream>>>(
        attno, blk_out_w + (size_t)i * 1048576, blk_out_b + i * 1024, t1,
        1024, 1024, 1024, xs, nullptr, nullptr, nullptr, nullptr);
    k_ln<<<dim3(1024), dim3(256), 0, stream>>>(
        t1, (const float*)nullptr, blk_n1_g + i * 1024, blk_n1_b + i * 1024, xs);
    k_cvt<<<dim3(4096), dim3(256), 0, stream>>>(ode_w1 + (size_t)i * 1048576, w16a, 1048576);
    k_cvt<<<dim3(4096), dim3(256), 0, stream>>>(ode_w2 + (size_t)i * 1048576, w16b, 1048576);
    k_zero<<<dim3(1), dim3(1), 0, stream>>>(bctr);
    k_ode<<<dim3(256), dim3(1024), 0, stream>>>(
        xs, odeo, w16a, ode_b1 + i * 1024, w16b, ode_b2 + i * 1024,
        ode_ng + i * 1024, ode_nb + i * 1024, lead, bctr);
    k_ln<<<dim3(1024), dim3(256), 0, stream>>>(
        xs, odeo, blk_n2_g + i * 1024, blk_n2_b + i * 1024, xs);
  }

  // ---- head ----
  k_ln<<<dim3(1024), dim3(256), 0, stream>>>(
      xs, (const float*)nullptr, norm_g, norm_b, xs);
  k_gemm<1><<<dim3(16, 16), dim3(256), 0, stream>>>(
      xs, h1_w, h1_b, y1, 1024, 1024, 1024, nullptr, nullptr, nullptr, nullptr, nullptr);
  k_gemm<1><<<dim3(16, 16), dim3(256), 0, stream>>>(
      y1, h2_w, h2_b, y2, 1024, 1024, 1024, nullptr, nullptr, nullptr, nullptr, nullptr);
  k_gemm<0><<<dim3(1, 16), dim3(256), 0, stream>>>(
      y2, hf_w, hf_b, y3, 1024, 20, 1024, nullptr, nullptr, nullptr, nullptr, nullptr);
  k_unpatch<<<dim3(80), dim3(256), 0, stream>>>(y3, (float*)d_out);
}

// Round 9
// 11818.680 us; speedup vs baseline: 1.6900x; 1.6900x over previous
//
#include <hip/hip_runtime.h>
#include <stdint.h>

// ============================================================================
// ConViTCast: B=2 V=5 H=32 W=64 P=2 D=1024 NH=16 hd=64 DEPTH=2 L=512 BL=1024
// Inputs f32, output f32. Round 9: k_ode v5 — minimize L2-miss bytes:
//  - 64 blocks x 16 tokens (min request volume, full M=16 tile)
//  - y in VGPRs, accr in LDS: ZERO global activation traffic (R6's Y/R
//    global stream polluted L2; R7's 256 blocks quadrupled requests)
//  - palindromic weight traversal per phase (cyclic LRU on a 4MB set over a
//    4MB L2 = 0% retention; reversing direction each phase reuses the tail)
//  - group-of-2 double-buffered B prefetch (~119 VGPR < 128 cap)
// R8 lesson: phase alignment is NOT the issue (barrier: FETCH unchanged).
// ============================================================================

#define NSTEPS 10
#define RESF 0.01f
#define EPSF 1e-5f

typedef unsigned short u16;
typedef __attribute__((ext_vector_type(8))) short bf16x8;
typedef __attribute__((ext_vector_type(4))) float f32x4;

__device__ __forceinline__ float b2f(u16 u) {
  return __uint_as_float(((uint32_t)u) << 16);
}
__device__ __forceinline__ u16 f2b(float f) {
  uint32_t x = __float_as_uint(f);
  uint32_t r = x + 0x7fffu + ((x >> 16) & 1u);  // round-to-nearest-even
  return (u16)(r >> 16);
}
__device__ __forceinline__ float red16(float v) {
  v += __shfl_xor(v, 1); v += __shfl_xor(v, 2);
  v += __shfl_xor(v, 4); v += __shfl_xor(v, 8);
  return v;
}

// f32 -> bf16 conversion (for ODE weights)
__global__ __launch_bounds__(256) void k_cvt(
    const float* __restrict__ in, u16* __restrict__ out16, int n) {
  int i = blockIdx.x * 256 + threadIdx.x;
  if (i < n) out16[i] = f2b(in[i]);
}

// ---------------------------------------------------------------------------
// Extract patches[m*20 + v*4 + p] from x[b,v,h,w]; m=b*512+l, l=hh*32+ww
// ---------------------------------------------------------------------------
__global__ __launch_bounds__(256) void k_patches(
    const float* __restrict__ x, float* __restrict__ patches) {
  int i = blockIdx.x * 256 + threadIdx.x;  // grid 80*256 = 20480
  int m = i / 20, r = i % 20;
  int v = r >> 2, p = r & 3;
  int b = m >> 9, l = m & 511;
  int hh = l >> 5, ww = l & 31;
  int pr = p >> 1, pc = p & 1;
  patches[i] = x[((size_t)(b * 5 + v) * 32 + hh * 2 + pr) * 64 + ww * 2 + pc];
}

// qvec = var_query @ Wq^T + bq   (grid 64)
__global__ __launch_bounds__(256) void k_qvec(
    const float* __restrict__ vq, const float* __restrict__ w,
    const float* __restrict__ bias, float* __restrict__ qvec) {
  int dq = blockIdx.x * 16 + (threadIdx.x >> 4);
  int lane = threadIdx.x & 15;
  float p = 0.f;
  for (int j = 0; j < 64; j++) {
    int d = lane + 16 * j;
    p += vq[d] * w[(size_t)dq * 1024 + d];
  }
  p = red16(p);
  if (lane == 0) qvec[dq] = p + bias[dq];
}

// qb[h] = sum_e qvec[h*64+e]*bk[h*64+e]   (grid 1)
__global__ __launch_bounds__(256) void k_qb(
    const float* __restrict__ qvec, const float* __restrict__ bk,
    float* __restrict__ qb) {
  int h = threadIdx.x >> 4, lane = threadIdx.x & 15;
  float p = 0.f;
  for (int e = lane; e < 64; e += 16) p += qvec[h * 64 + e] * bk[h * 64 + e];
  p = red16(p);
  if (lane == 0) qb[h] = p;
}

// u[h][d] = sum_e qvec[h*64+e] * Wk[h*64+e][d]   (grid 64)
__global__ __launch_bounds__(256) void k_u(
    const float* __restrict__ qvec, const float* __restrict__ wk,
    float* __restrict__ u) {
  int d = blockIdx.x * 16 + (threadIdx.x & 15);
  int h = threadIdx.x >> 4;
  float acc = 0.f;
  for (int e = 0; e < 64; e++)
    acc += qvec[h * 64 + e] * wk[(size_t)(h * 64 + e) * 1024 + d];
  u[h * 1024 + d] = acc;
}

// PU[(v*16+h)*4+p] = 0.125*sum_d pw[v,d,p]*u[h,d]
// C0[v*16+h]       = 0.125*(sum_d (pb+ve)[v,d]*u[h,d] + qb[h])     (grid 80)
__global__ __launch_bounds__(256) void k_pu(
    const float* __restrict__ pw, const float* __restrict__ pb,
    const float* __restrict__ ve, const float* __restrict__ u,
    const float* __restrict__ qb, float* __restrict__ PU,
    float* __restrict__ C0) {
  int v = blockIdx.x / 16, h = blockIdx.x % 16;
  int t = threadIdx.x;
  float a0 = 0, a1 = 0, a2 = 0, a3 = 0, ac = 0;
  for (int d = t; d < 1024; d += 256) {
    float uu = u[h * 1024 + d];
    const float* p4 = pw + ((size_t)v * 1024 + d) * 4;
    a0 += p4[0] * uu; a1 += p4[1] * uu; a2 += p4[2] * uu; a3 += p4[3] * uu;
    ac += (pb[v * 1024 + d] + ve[v * 1024 + d]) * uu;
  }
  for (int off = 1; off < 64; off <<= 1) {
    a0 += __shfl_xor(a0, off); a1 += __shfl_xor(a1, off);
    a2 += __shfl_xor(a2, off); a3 += __shfl_xor(a3, off);
    ac += __shfl_xor(ac, off);
  }
  __shared__ float r[4][5];
  if ((t & 63) == 0) {
    int w = t >> 6;
    r[w][0] = a0; r[w][1] = a1; r[w][2] = a2; r[w][3] = a3; r[w][4] = ac;
  }
  __syncthreads();
  if (t == 0) {
    float s[5];
    for (int j = 0; j < 5; j++) s[j] = r[0][j] + r[1][j] + r[2][j] + r[3][j];
    float* pu = PU + (v * 16 + h) * 4;
    pu[0] = 0.125f * s[0]; pu[1] = 0.125f * s[1];
    pu[2] = 0.125f * s[2]; pu[3] = 0.125f * s[3];
    C0[v * 16 + h] = 0.125f * (s[4] + qb[h]);
  }
}

// PW[(v*1024+col)*4+p] = sum_d Wv[col,d]*pw[v,d,p]
// CV[v*1024+col]       = sum_d Wv[col,d]*(pb+ve)[v,d] + bv[col]    (grid 5120)
__global__ __launch_bounds__(256) void k_pw(
    const float* __restrict__ wv, const float* __restrict__ bv,
    const float* __restrict__ pw, const float* __restrict__ pb,
    const float* __restrict__ ve, float* __restrict__ PW,
    float* __restrict__ CV) {
  int v = blockIdx.x >> 10, col = blockIdx.x & 1023;
  int t = threadIdx.x;
  const float* wr = wv + (size_t)col * 1024;
  float4 w4 = *(const float4*)(wr + t * 4);
  float a0 = 0, a1 = 0, a2 = 0, a3 = 0, ac = 0;
#pragma unroll
  for (int j = 0; j < 4; j++) {
    int d = t * 4 + j;
    float wj = (j == 0) ? w4.x : (j == 1) ? w4.y : (j == 2) ? w4.z : w4.w;
    const float* p4 = pw + ((size_t)v * 1024 + d) * 4;
    a0 += wj * p4[0]; a1 += wj * p4[1]; a2 += wj * p4[2]; a3 += wj * p4[3];
    ac += wj * (pb[v * 1024 + d] + ve[v * 1024 + d]);
  }
  for (int off = 1; off < 64; off <<= 1) {
    a0 += __shfl_xor(a0, off); a1 += __shfl_xor(a1, off);
    a2 += __shfl_xor(a2, off); a3 += __shfl_xor(a3, off);
    ac += __shfl_xor(ac, off);
  }
  __shared__ float r[4][5];
  if ((t & 63) == 0) {
    int w = t >> 6;
    r[w][0] = a0; r[w][1] = a1; r[w][2] = a2; r[w][3] = a3; r[w][4] = ac;
  }
  __syncthreads();
  if (t == 0) {
    float s[5];
    for (int j = 0; j < 5; j++) s[j] = r[0][j] + r[1][j] + r[2][j] + r[3][j];
    float* o = PW + ((size_t)(v * 1024 + col)) * 4;
    o[0] = s[0]; o[1] = s[1]; o[2] = s[2]; o[3] = s[3];
    CV[v * 1024 + col] = s[4] + bv[col];
  }
}

// scores s[v][h] = patches[m,v]·PU[v,h] + C0[v,h]; softmax over v
// -> amat[m*80 + h*5 + v]                                          (grid 1024)
__global__ __launch_bounds__(256) void k_scoresm(
    const float* __restrict__ patches, const float* __restrict__ PU,
    const float* __restrict__ C0, float* __restrict__ amat) {
  __shared__ float pat[20];
  __shared__ float sa[16][8];
  int m = blockIdx.x, t = threadIdx.x;
  if (t < 20) pat[t] = patches[m * 20 + t];
  __syncthreads();
  if (t < 80) {
    int v = t / 16, h = t % 16;
    const float* pu = PU + (v * 16 + h) * 4;
    float s = C0[v * 16 + h] + pat[v * 4 + 0] * pu[0] + pat[v * 4 + 1] * pu[1]
            + pat[v * 4 + 2] * pu[2] + pat[v * 4 + 3] * pu[3];
    sa[h][v] = s;
  }
  __syncthreads();
  if (t < 16) {
    float mx = sa[t][0];
    for (int v = 1; v < 5; v++) mx = fmaxf(mx, sa[t][v]);
    float e[5], sum = 0.f;
    for (int v = 0; v < 5; v++) { e[v] = __expf(sa[t][v] - mx); sum += e[v]; }
    float inv = 1.f / sum;
    for (int v = 0; v < 5; v++) amat[m * 80 + t * 5 + v] = e[v] * inv;
  }
}

// agg[m,c] = sum_v amat[m,h(c),v] * (patches[m,v]·PW[v,c] + CV[v,c]) (grid 1024)
__global__ __launch_bounds__(256) void k_agg(
    const float* __restrict__ patches, const float* __restrict__ PW,
    const float* __restrict__ CV, const float* __restrict__ amat,
    float* __restrict__ agg) {
  __shared__ float pat[20];
  __shared__ float am[80];
  int m = blockIdx.x, t = threadIdx.x;
  if (t < 20) pat[t] = patches[m * 20 + t];
  if (t < 80) am[t] = amat[m * 80 + t];
  __syncthreads();
  int c0 = t * 4;
#pragma unroll
  for (int j = 0; j < 4; j++) {
    int c = c0 + j;
    int h = c >> 6;
    float acc = 0.f;
#pragma unroll
    for (int v = 0; v < 5; v++) {
      float4 w4 = *(const float4*)(PW + ((size_t)(v * 1024 + c)) * 4);
      float val = pat[v * 4 + 0] * w4.x + pat[v * 4 + 1] * w4.y
                + pat[v * 4 + 2] * w4.z + pat[v * 4 + 3] * w4.w
                + CV[v * 1024 + c];
      acc += am[h * 5 + v] * val;
    }
    agg[(size_t)m * 1024 + c] = acc;
  }
}

// ---------------------------------------------------------------------------
// Generic fp32 GEMM: C[M][N] = A[M][K] @ W[N][K]^T + bias, epilogues.
// EPI: 0 plain, 1 gelu(exact), 2 +resid, 3 +pos+lt
// ---------------------------------------------------------------------------
template <int EPI>
__global__ __launch_bounds__(256) void k_gemm(
    const float* __restrict__ A, const float* __restrict__ W,
    const float* __restrict__ bias, float* __restrict__ C,
    int M, int N, int K,
    const float* __restrict__ resid,
    const float* __restrict__ pos, const float* __restrict__ ltw,
    const float* __restrict__ ltb, const float* __restrict__ lead) {
  __shared__ float As[16][68];
  __shared__ float Ws[16][68];
  int m0 = blockIdx.y * 64, n0 = blockIdx.x * 64;
  int tid = threadIdx.x;
  int tx = tid & 15, ty = tid >> 4;
  int lr = tid & 63, lk = (tid >> 6) * 4;
  float acc[4][4] = {};
  for (int k0 = 0; k0 < K; k0 += 16) {
    float4 av = *(const float4*)(A + (size_t)(m0 + lr) * K + k0 + lk);
    float4 wv = {0.f, 0.f, 0.f, 0.f};
    if (n0 + lr < N) {
      wv = *(const float4*)(W + (size_t)(n0 + lr) * K + k0 + lk);
    }
    __syncthreads();
    As[lk + 0][lr] = av.x; As[lk + 1][lr] = av.y;
    As[lk + 2][lr] = av.z; As[lk + 3][lr] = av.w;
    Ws[lk + 0][lr] = wv.x; Ws[lk + 1][lr] = wv.y;
    Ws[lk + 2][lr] = wv.z; Ws[lk + 3][lr] = wv.w;
    __syncthreads();
#pragma unroll
    for (int kk = 0; kk < 16; kk++) {
      float4 a = *(const float4*)&As[kk][ty * 4];
      float4 b = *(const float4*)&Ws[kk][tx * 4];
      acc[0][0] += a.x * b.x; acc[0][1] += a.x * b.y; acc[0][2] += a.x * b.z; acc[0][3] += a.x * b.w;
      acc[1][0] += a.y * b.x; acc[1][1] += a.y * b.y; acc[1][2] += a.y * b.z; acc[1][3] += a.y * b.w;
      acc[2][0] += a.z * b.x; acc[2][1] += a.z * b.y; acc[2][2] += a.z * b.z; acc[2][3] += a.z * b.w;
      acc[3][0] += a.w * b.x; acc[3][1] += a.w * b.y; acc[3][2] += a.w * b.z; acc[3][3] += a.w * b.w;
    }
  }
#pragma unroll
  for (int ii = 0; ii < 4; ii++) {
    int m = m0 + ty * 4 + ii;
#pragma unroll
    for (int jj = 0; jj < 4; jj++) {
      int n = n0 + tx * 4 + jj;
      if (n >= N) continue;
      float v = acc[ii][jj] + bias[n];
      if (EPI == 1) v = 0.5f * v * (1.f + erff(v * 0.70710678118f));
      if (EPI == 2) v += resid[(size_t)m * N + n];
      if (EPI == 3) {
        int b = m >> 9, l = m & 511;
        v += pos[(size_t)l * 1024 + n] + ltw[n] * lead[b] + ltb[n];
      }
      C[(size_t)m * N + n] = v;
    }
  }
}

// ---------------------------------------------------------------------------
// LayerNorm over D=1024 (grid M). In-place safe.
// ---------------------------------------------------------------------------
__global__ __launch_bounds__(256) void k_ln(
    const float* __restrict__ src, const float* __restrict__ add,
    const float* __restrict__ g, const float* __restrict__ bb,
    float* __restrict__ dst) {
  __shared__ float red[8];
  int m = blockIdx.x, tid = threadIdx.x;
  float4 x = *(const float4*)(src + (size_t)m * 1024 + tid * 4);
  if (add) {
    float4 a2 = *(const float4*)(add + (size_t)m * 1024 + tid * 4);
    x.x += a2.x; x.y += a2.y; x.z += a2.z; x.w += a2.w;
  }
  float s1 = x.x + x.y + x.z + x.w;
  float s2 = x.x * x.x + x.y * x.y + x.z * x.z + x.w * x.w;
  for (int off = 1; off < 64; off <<= 1) {
    s1 += __shfl_xor(s1, off); s2 += __shfl_xor(s2, off);
  }
  if ((tid & 63) == 0) { red[(tid >> 6) * 2] = s1; red[(tid >> 6) * 2 + 1] = s2; }
  __syncthreads();
  s1 = red[0] + red[2] + red[4] + red[6];
  s2 = red[1] + red[3] + red[5] + red[7];
  float mean = s1 * (1.f / 1024.f);
  float var = s2 * (1.f / 1024.f) - mean * mean;
  float rstd = rsqrtf(var + EPSF);
  int c = tid * 4;
  float4 o;
  o.x = (x.x - mean) * rstd * g[c + 0] + bb[c + 0];
  o.y = (x.y - mean) * rstd * g[c + 1] + bb[c + 1];
  o.z = (x.z - mean) * rstd * g[c + 2] + bb[c + 2];
  o.w = (x.w - mean) * rstd * g[c + 3] + bb[c + 3];
  *(float4*)(dst + (size_t)m * 1024 + c) = o;
}

// ---------------------------------------------------------------------------
// Patch attention: per (b,h,ntile16). Two-pass softmax with S in LDS.
// ---------------------------------------------------------------------------
__global__ __launch_bounds__(256) void k_attn(
    const float* __restrict__ qkv, float* __restrict__ o) {
  __shared__ float Q[16][68];
  __shared__ float S[16][516];
  __shared__ float KV[32][68];
  int bid = blockIdx.x;
  int nt = bid & 31, h = (bid >> 5) & 15, b = bid >> 9;
  int tid = threadIdx.x;
  for (int i = tid; i < 16 * 64; i += 256) {
    int r = i >> 6, e = i & 63;
    Q[r][e] = qkv[(size_t)(b * 512 + nt * 16 + r) * 3072 + h * 64 + e];
  }
  __syncthreads();
  int r = tid >> 4, lane = tid & 15;
  for (int kt = 0; kt < 16; kt++) {
    for (int i = tid; i < 32 * 64; i += 256) {
      int rr = i >> 6, e = i & 63;
      KV[rr][e] = qkv[(size_t)(b * 512 + kt * 32 + rr) * 3072 + 1024 + h * 64 + e];
    }
    __syncthreads();
    for (int jj = lane; jj < 32; jj += 16) {
      float acc = 0.f;
#pragma unroll 8
      for (int e = 0; e < 64; e++) acc += Q[r][e] * KV[jj][e];
      S[r][kt * 32 + jj] = acc * 0.125f;
    }
    __syncthreads();
  }
  float mx = -1e30f;
  for (int j = lane; j < 512; j += 16) mx = fmaxf(mx, S[r][j]);
  for (int off = 1; off < 16; off <<= 1) mx = fmaxf(mx, __shfl_xor(mx, off));
  float sum = 0.f;
  for (int j = lane; j < 512; j += 16) {
    float e = __expf(S[r][j] - mx);
    S[r][j] = e; sum += e;
  }
  sum = red16(sum);
  float inv = 1.f / sum;
  int e0 = lane * 4;
  float4 accv = {0.f, 0.f, 0.f, 0.f};
  for (int kt = 0; kt < 16; kt++) {
    __syncthreads();
    for (int i = tid; i < 32 * 64; i += 256) {
      int rr = i >> 6, e = i & 63;
      KV[rr][e] = qkv[(size_t)(b * 512 + kt * 32 + rr) * 3072 + 2048 + h * 64 + e];
    }
    __syncthreads();
#pragma unroll 8
    for (int j = 0; j < 32; j++) {
      float p = S[r][kt * 32 + j] * inv;
      accv.x += p * KV[j][e0 + 0]; accv.y += p * KV[j][e0 + 1];
      accv.z += p * KV[j][e0 + 2]; accv.w += p * KV[j][e0 + 3];
    }
  }
  float* op = o + (size_t)(b * 512 + nt * 16 + r) * 1024 + h * 64 + e0;
  op[0] = accv.x; op[1] = accv.y; op[2] = accv.z; op[3] = accv.w;
}

// ---------------------------------------------------------------------------
// ODE persistent kernel v5. 64 blocks x 1024 thr (16 waves); block owns 16
// tokens (full M=16 tile). y in VGPRs (wave=token, lane owns 16 ch); accr in
// LDS. Palindromic k-traversal per phase. Group-of-2 double-buffered B PF.
// LDS: bufA 32K + bufH 32K + Rs 64K = 128K (1 block/CU).
// ---------------------------------------------------------------------------
__device__ __forceinline__ int swz(int m, int c) {
  int g = c >> 3;
  g = (g & ~7) | ((g ^ m) & 7);
  return m * 1024 + g * 8 + (c & 7);
}
__device__ __forceinline__ int swz8(int m, int k) {  // k multiple of 8
  int g = k >> 3;
  g = (g & ~7) | ((g ^ m) & 7);
  return m * 1024 + g * 8;
}

__global__ __launch_bounds__(1024, 4) void k_ode(
    const float* __restrict__ xs, float* __restrict__ out,
    const u16* __restrict__ w1, const float* __restrict__ b1,
    const u16* __restrict__ w2, const float* __restrict__ b2,
    const float* __restrict__ ng, const float* __restrict__ nb,
    const float* __restrict__ lead) {
  __shared__ u16 bufA[16 * 1024];
  __shared__ u16 bufH[16 * 1024];
  __shared__ float Rs[16][1024];
  int tid = threadIdx.x;
  int m0 = blockIdx.x * 16;
  int idxb = (int)roundf(lead[m0 >> 9] * 100.0f);
  int wvid = tid >> 6, lane = tid & 63;
  int col = lane & 15, quad = lane >> 4;
  int cbase = wvid * 64 + col;
  int ec0 = lane * 16;
  float y[16];
  {
    const float* yp = xs + (size_t)(m0 + wvid) * 1024 + ec0;
    float* op = out + (size_t)(m0 + wvid) * 1024 + ec0;
#pragma unroll
    for (int j = 0; j < 16; j++) {
      y[j] = yp[j]; op[j] = y[j];
      bufA[swz(wvid, ec0 + j)] = f2b(y[j]);
    }
  }
  __syncthreads();
  const float h6 = RESF / 6.0f;

  for (int s = 0; s < NSTEPS; s++) {
    for (int ph = 0; ph < 4; ph++) {
      int dir = (s * 4 + ph) & 1;  // palindromic stream direction
      // ---- GEMM1: h = relu(bufA @ w1^T + b1) -> bufH ----
      {
        f32x4 acc[4] = {};
        const u16* wp[4];
#pragma unroll
        for (int ct = 0; ct < 4; ct++)
          wp[ct] = w1 + (size_t)(cbase + ct * 16) * 1024 + quad * 8;
        bf16x8 cur[8], nxt[8];
#pragma unroll
        for (int u = 0; u < 2; u++) {
          int koff = dir ? (31 - u) * 32 : u * 32;
#pragma unroll
          for (int ct = 0; ct < 4; ct++)
            cur[u * 4 + ct] = *(const bf16x8*)(wp[ct] + koff);
        }
#pragma unroll
        for (int g = 0; g < 16; g++) {
          if (g < 15) {
#pragma unroll
            for (int u = 0; u < 2; u++) {
              int i = (g + 1) * 2 + u;
              int koff = dir ? (31 - i) * 32 : i * 32;
#pragma unroll
              for (int ct = 0; ct < 4; ct++)
                nxt[u * 4 + ct] = *(const bf16x8*)(wp[ct] + koff);
            }
          }
#pragma unroll
          for (int u = 0; u < 2; u++) {
            int i = g * 2 + u;
            int kk = dir ? (31 - i) : i;
            bf16x8 aF = *(const bf16x8*)(bufA + swz8(col, kk * 32 + quad * 8));
#pragma unroll
            for (int ct = 0; ct < 4; ct++)
              acc[ct] = __builtin_amdgcn_mfma_f32_16x16x32_bf16(
                  aF, cur[u * 4 + ct], acc[ct], 0, 0, 0);
          }
          if (g < 15) {
#pragma unroll
            for (int q = 0; q < 8; q++) cur[q] = nxt[q];
          }
        }
#pragma unroll
        for (int ct = 0; ct < 4; ct++) {
          int c = cbase + ct * 16;
          float bv = b1[c];
#pragma unroll
          for (int rr = 0; rr < 4; rr++)
            bufH[swz(quad * 4 + rr, c)] = f2b(fmaxf(acc[ct][rr] + bv, 0.f));
        }
      }
      __syncthreads();
      // ---- GEMM2: z = bufH @ w2^T ----
      f32x4 acc2[4] = {};
      {
        const u16* wp[4];
#pragma unroll
        for (int ct = 0; ct < 4; ct++)
          wp[ct] = w2 + (size_t)(cbase + ct * 16) * 1024 + quad * 8;
        bf16x8 cur[8], nxt[8];
#pragma unroll
        for (int u = 0; u < 2; u++) {
          int koff = dir ? (31 - u) * 32 : u * 32;
#pragma unroll
          for (int ct = 0; ct < 4; ct++)
            cur[u * 4 + ct] = *(const bf16x8*)(wp[ct] + koff);
        }
#pragma unroll
        for (int g = 0; g < 16; g++) {
          if (g < 15) {
#pragma unroll
            for (int u = 0; u < 2; u++) {
              int i = (g + 1) * 2 + u;
              int koff = dir ? (31 - i) * 32 : i * 32;
#pragma unroll
              for (int ct = 0; ct < 4; ct++)
                nxt[u * 4 + ct] = *(const bf16x8*)(wp[ct] + koff);
            }
          }
#pragma unroll
          for (int u = 0; u < 2; u++) {
            int i = g * 2 + u;
            int kk = dir ? (31 - i) : i;
            bf16x8 aF = *(const bf16x8*)(bufH + swz8(col, kk * 32 + quad * 8));
#pragma unroll
            for (int ct = 0; ct < 4; ct++)
              acc2[ct] = __builtin_amdgcn_mfma_f32_16x16x32_bf16(
                  aF, cur[u * 4 + ct], acc2[ct], 0, 0, 0);
          }
          if (g < 15) {
#pragma unroll
            for (int q = 0; q < 8; q++) cur[q] = nxt[q];
          }
        }
      }
      __syncthreads();  // all waves done READING bufH before overwrite
      // ---- z = acc2 + b2 + resid(bufA) -> bufH ----
#pragma unroll
      for (int ct = 0; ct < 4; ct++) {
        int c = cbase + ct * 16;
        float bv = b2[c];
#pragma unroll
        for (int rr = 0; rr < 4; rr++) {
          int mr = quad * 4 + rr;
          float z = acc2[ct][rr] + bv + b2f(bufA[swz(mr, c)]);
          bufH[swz(mr, c)] = f2b(z);
        }
      }
      __syncthreads();
      // ---- epilogue: LN (wave = token) + RK4 state update ----
      {
        float z16[16];
        float s1 = 0.f, s2 = 0.f;
#pragma unroll
        for (int j = 0; j < 16; j++) {
          z16[j] = b2f(bufH[swz(wvid, ec0 + j)]);
          s1 += z16[j]; s2 += z16[j] * z16[j];
        }
        for (int off = 1; off < 64; off <<= 1) {
          s1 += __shfl_xor(s1, off); s2 += __shfl_xor(s2, off);
        }
        float mean = s1 * (1.f / 1024.f);
        float var = s2 * (1.f / 1024.f) - mean * mean;
        float rstd = rsqrtf(var + EPSF);
        float cf = (ph < 2) ? 0.5f * RESF : RESF;
#pragma unroll
        for (int j = 0; j < 16; j++) {
          int c = ec0 + j;
          float k = (z16[j] - mean) * rstd * ng[c] + nb[c];
          float nv;
          if (ph == 0)      { Rs[wvid][c] = k;        nv = y[j] + cf * k; }
          else if (ph < 3)  { Rs[wvid][c] += 2.f * k; nv = y[j] + cf * k; }
          else              { y[j] += h6 * (Rs[wvid][c] + k); nv = y[j]; }
          bufA[swz(wvid, c)] = f2b(nv);
        }
        if (ph == 3 && (s + 1) == idxb) {
          float* op = out + (size_t)(m0 + wvid) * 1024 + ec0;
#pragma unroll
          for (int j = 0; j < 16; j++) op[j] = y[j];
        }
      }
      __syncthreads();
    }
  }
}

// ---------------------------------------------------------------------------
// Unpatchify: y3[m][p*10+q*5+c] -> out[b][c][hh*2+p][ww*2+q], FLOAT32
// ---------------------------------------------------------------------------
__global__ __launch_bounds__(256) void k_unpatch(
    const float* __restrict__ y3, float* __restrict__ outp) {
  int o = blockIdx.x * 256 + threadIdx.x;
  if (o >= 20480) return;
  int b = o / 10240;
  int c = (o / 2048) % 5;
  int hrow = (o / 64) % 32;
  int wcol = o % 64;
  int hh = hrow >> 1, p = hrow & 1, ww = wcol >> 1, q = wcol & 1;
  int m2 = b * 512 + hh * 32 + ww;
  int colj = p * 10 + q * 5 + c;
  outp[o] = y3[(size_t)m2 * 20 + colj];
}

// ===========================================================================
extern "C" void kernel_launch(void* const* d_in, const int* in_sizes, int n_in,
                              void* d_out, int out_size, void* d_ws, size_t ws_size,
                              hipStream_t stream) {
  const float* x         = (const float*)d_in[0];
  const float* lead      = (const float*)d_in[1];
  const float* patch_w   = (const float*)d_in[2];
  const float* patch_b   = (const float*)d_in[3];
  const float* var_embed = (const float*)d_in[4];
  const float* var_query = (const float*)d_in[5];
  const float* agg_in_w  = (const float*)d_in[6];
  const float* agg_in_b  = (const float*)d_in[7];
  const float* agg_out_w = (const float*)d_in[8];
  const float* agg_out_b = (const float*)d_in[9];
  const float* pos_embed = (const float*)d_in[10];
  const float* lt_w      = (const float*)d_in[11];
  const float* lt_b      = (const float*)d_in[12];
  const float* blk_qkv_w = (const float*)d_in[13];
  const float* blk_qkv_b = (const float*)d_in[14];
  const float* blk_out_w = (const float*)d_in[15];
  const float* blk_out_b = (const float*)d_in[16];
  const float* blk_n1_g  = (const float*)d_in[17];
  const float* blk_n1_b  = (const float*)d_in[18];
  const float* blk_n2_g  = (const float*)d_in[19];
  const float* blk_n2_b  = (const float*)d_in[20];
  const float* ode_w1    = (const float*)d_in[21];
  const float* ode_b1    = (const float*)d_in[22];
  const float* ode_w2    = (const float*)d_in[23];
  const float* ode_b2    = (const float*)d_in[24];
  const float* ode_ng    = (const float*)d_in[25];
  const float* ode_nb    = (const float*)d_in[26];
  const float* norm_g    = (const float*)d_in[27];
  const float* norm_b    = (const float*)d_in[28];
  const float* h1_w      = (const float*)d_in[29];
  const float* h1_b      = (const float*)d_in[30];
  const float* h2_w      = (const float*)d_in[31];
  const float* h2_b      = (const float*)d_in[32];
  const float* hf_w      = (const float*)d_in[33];
  const float* hf_b      = (const float*)d_in[34];
  (void)in_sizes; (void)n_in; (void)out_size; (void)ws_size;

  float* ws = (float*)d_ws;
  float* patches = ws + 0;         // 20480
  float* qvec    = ws + 20480;     // 1024
  float* qb      = ws + 21504;     // 256 (16 used)
  float* u       = ws + 21760;     // 16384
  float* PU      = ws + 38144;     // 320
  float* C0      = ws + 38464;     // 80 (pad to 40960)
  float* amat    = ws + 40960;     // 81920
  float* PW      = ws + 122880;    // 20480
  float* CV      = ws + 143360;    // 5120  (end 148480 < 3145728)
  float* agg     = ws + 3145728;   // 1048576 (attno slot; dead by then)
  float* qkv   = ws + 0;           // 3145728
  float* attno = ws + 3145728;     // 1048576
  float* t1    = ws + 4194304;     // 1048576
  float* odeo  = ws + 5242880;     // 1048576
  float* xs    = ws + 6291456;     // 1048576
  u16*   w16a  = (u16*)(ws + 7340032);  // per-depth w1 (bf16)
  u16*   w16b  = (u16*)(ws + 7864320);  // per-depth w2 (bf16)
  float* y1 = ws + 0;
  float* y2 = ws + 1048576;
  float* y3 = ws + 2097152;        // 20480

  // ---- stage 1 ----
  k_patches<<<dim3(80), dim3(256), 0, stream>>>(x, patches);
  k_qvec<<<dim3(64), dim3(256), 0, stream>>>(var_query, agg_in_w, agg_in_b, qvec);
  k_qb<<<dim3(1), dim3(256), 0, stream>>>(qvec, agg_in_b + 1024, qb);
  k_u<<<dim3(64), dim3(256), 0, stream>>>(qvec, agg_in_w + (size_t)1024 * 1024, u);
  k_pu<<<dim3(80), dim3(256), 0, stream>>>(patch_w, patch_b, var_embed, u, qb, PU, C0);
  k_pw<<<dim3(5120), dim3(256), 0, stream>>>(
      agg_in_w + (size_t)2048 * 1024, agg_in_b + 2048, patch_w, patch_b,
      var_embed, PW, CV);
  k_scoresm<<<dim3(1024), dim3(256), 0, stream>>>(patches, PU, C0, amat);
  k_agg<<<dim3(1024), dim3(256), 0, stream>>>(patches, PW, CV, amat, agg);
  k_gemm<3><<<dim3(16, 16), dim3(256), 0, stream>>>(
      agg, agg_out_w, agg_out_b, xs, 1024, 1024, 1024,
      nullptr, pos_embed, lt_w, lt_b, lead);

  // ---- transformer blocks ----
  for (int i = 0; i < 2; i++) {
    k_gemm<0><<<dim3(48, 16), dim3(256), 0, stream>>>(
        xs, blk_qkv_w + (size_t)i * 3072 * 1024, blk_qkv_b + i * 3072, qkv,
        1024, 3072, 1024, nullptr, nullptr, nullptr, nullptr, nullptr);
    k_attn<<<dim3(1024), dim3(256), 0, stream>>>(qkv, attno);
    k_gemm<2><<<dim3(16, 16), dim3(256), 0, stream>>>(
        attno, blk_out_w + (size_t)i * 1048576, blk_out_b + i * 1024, t1,
        1024, 1024, 1024, xs, nullptr, nullptr, nullptr, nullptr);
    k_ln<<<dim3(1024), dim3(256), 0, stream>>>(
        t1, (const float*)nullptr, blk_n1_g + i * 1024, blk_n1_b + i * 1024, xs);
    k_cvt<<<dim3(4096), dim3(256), 0, stream>>>(ode_w1 + (size_t)i * 1048576, w16a, 1048576);
    k_cvt<<<dim3(4096), dim3(256), 0, stream>>>(ode_w2 + (size_t)i * 1048576, w16b, 1048576);
    k_ode<<<dim3(64), dim3(1024), 0, stream>>>(
        xs, odeo, w16a, ode_b1 + i * 1024, w16b, ode_b2 + i * 1024,
        ode_ng + i * 1024, ode_nb + i * 1024, lead);
    k_ln<<<dim3(1024), dim3(256), 0, stream>>>(
        xs, odeo, blk_n2_g + i * 1024, blk_n2_b + i * 1024, xs);
  }

  // ---- head ----
  k_ln<<<dim3(1024), dim3(256), 0, stream>>>(
      xs, (const float*)nullptr, norm_g, norm_b, xs);
  k_gemm<1><<<dim3(16, 16), dim3(256), 0, stream>>>(
      xs, h1_w, h1_b, y1, 1024, 1024, 1024, nullptr, nullptr, nullptr, nullptr, nullptr);
  k_gemm<1><<<dim3(16, 16), dim3(256), 0, stream>>>(
      y1, h2_w, h2_b, y2, 1024, 1024, 1024, nullptr, nullptr, nullptr, nullptr, nullptr);
  k_gemm<0><<<dim3(1, 16), dim3(256), 0, stream>>>(
      y2, hf_w, hf_b, y3, 1024, 20, 1024, nullptr, nullptr, nullptr, nullptr, nullptr);
  k_unpatch<<<dim3(80), dim3(256), 0, stream>>>(y3, (float*)d_out);
}

// Round 10
// 9688.435 us; speedup vs baseline: 2.0616x; 1.2199x over previous
//
#include <hip/hip_runtime.h>
#include <stdint.h>

// ============================================================================
// ConViTCast: B=2 V=5 H=32 W=64 P=2 D=1024 NH=16 hd=64 DEPTH=2 L=512 BL=1024
// Inputs f32, output f32. Round 10: k_ode v6 — async LDS weight staging.
// R9 evidence: VGPR_Count=64 -> compiler collapsed the register double-buffer
// (needed ~110 VGPRs) -> serial per-group L2 latency exposure (131us/phase vs
// ~30us port floor). v6 streams weights via __builtin_amdgcn_global_load_lds
// (width 16, m97 pattern): 64 double-buffered 32KB chunks per GEMM,
// barrier -> stage(next) -> compute(cur). Rs moved to VGPR accr[16].
// LDS: bufA 32K + bufH 32K + Wbuf 64K = 128K. Palindromic chunk order kept.
// ============================================================================

#define NSTEPS 10
#define RESF 0.01f
#define EPSF 1e-5f

typedef unsigned short u16;
typedef __attribute__((ext_vector_type(8))) short bf16x8;
typedef __attribute__((ext_vector_type(4))) float f32x4;

__device__ __forceinline__ float b2f(u16 u) {
  return __uint_as_float(((uint32_t)u) << 16);
}
__device__ __forceinline__ u16 f2b(float f) {
  uint32_t x = __float_as_uint(f);
  uint32_t r = x + 0x7fffu + ((x >> 16) & 1u);  // round-to-nearest-even
  return (u16)(r >> 16);
}
__device__ __forceinline__ float red16(float v) {
  v += __shfl_xor(v, 1); v += __shfl_xor(v, 2);
  v += __shfl_xor(v, 4); v += __shfl_xor(v, 8);
  return v;
}

// f32 -> bf16 conversion (for ODE weights)
__global__ __launch_bounds__(256) void k_cvt(
    const float* __restrict__ in, u16* __restrict__ out16, int n) {
  int i = blockIdx.x * 256 + threadIdx.x;
  if (i < n) out16[i] = f2b(in[i]);
}

// ---------------------------------------------------------------------------
// Extract patches[m*20 + v*4 + p] from x[b,v,h,w]; m=b*512+l, l=hh*32+ww
// ---------------------------------------------------------------------------
__global__ __launch_bounds__(256) void k_patches(
    const float* __restrict__ x, float* __restrict__ patches) {
  int i = blockIdx.x * 256 + threadIdx.x;  // grid 80*256 = 20480
  int m = i / 20, r = i % 20;
  int v = r >> 2, p = r & 3;
  int b = m >> 9, l = m & 511;
  int hh = l >> 5, ww = l & 31;
  int pr = p >> 1, pc = p & 1;
  patches[i] = x[((size_t)(b * 5 + v) * 32 + hh * 2 + pr) * 64 + ww * 2 + pc];
}

// qvec = var_query @ Wq^T + bq   (grid 64)
__global__ __launch_bounds__(256) void k_qvec(
    const float* __restrict__ vq, const float* __restrict__ w,
    const float* __restrict__ bias, float* __restrict__ qvec) {
  int dq = blockIdx.x * 16 + (threadIdx.x >> 4);
  int lane = threadIdx.x & 15;
  float p = 0.f;
  for (int j = 0; j < 64; j++) {
    int d = lane + 16 * j;
    p += vq[d] * w[(size_t)dq * 1024 + d];
  }
  p = red16(p);
  if (lane == 0) qvec[dq] = p + bias[dq];
}

// qb[h] = sum_e qvec[h*64+e]*bk[h*64+e]   (grid 1)
__global__ __launch_bounds__(256) void k_qb(
    const float* __restrict__ qvec, const float* __restrict__ bk,
    float* __restrict__ qb) {
  int h = threadIdx.x >> 4, lane = threadIdx.x & 15;
  float p = 0.f;
  for (int e = lane; e < 64; e += 16) p += qvec[h * 64 + e] * bk[h * 64 + e];
  p = red16(p);
  if (lane == 0) qb[h] = p;
}

// u[h][d] = sum_e qvec[h*64+e] * Wk[h*64+e][d]   (grid 64)
__global__ __launch_bounds__(256) void k_u(
    const float* __restrict__ qvec, const float* __restrict__ wk,
    float* __restrict__ u) {
  int d = blockIdx.x * 16 + (threadIdx.x & 15);
  int h = threadIdx.x >> 4;
  float acc = 0.f;
  for (int e = 0; e < 64; e++)
    acc += qvec[h * 64 + e] * wk[(size_t)(h * 64 + e) * 1024 + d];
  u[h * 1024 + d] = acc;
}

// PU[(v*16+h)*4+p] = 0.125*sum_d pw[v,d,p]*u[h,d]
// C0[v*16+h]       = 0.125*(sum_d (pb+ve)[v,d]*u[h,d] + qb[h])     (grid 80)
__global__ __launch_bounds__(256) void k_pu(
    const float* __restrict__ pw, const float* __restrict__ pb,
    const float* __restrict__ ve, const float* __restrict__ u,
    const float* __restrict__ qb, float* __restrict__ PU,
    float* __restrict__ C0) {
  int v = blockIdx.x / 16, h = blockIdx.x % 16;
  int t = threadIdx.x;
  float a0 = 0, a1 = 0, a2 = 0, a3 = 0, ac = 0;
  for (int d = t; d < 1024; d += 256) {
    float uu = u[h * 1024 + d];
    const float* p4 = pw + ((size_t)v * 1024 + d) * 4;
    a0 += p4[0] * uu; a1 += p4[1] * uu; a2 += p4[2] * uu; a3 += p4[3] * uu;
    ac += (pb[v * 1024 + d] + ve[v * 1024 + d]) * uu;
  }
  for (int off = 1; off < 64; off <<= 1) {
    a0 += __shfl_xor(a0, off); a1 += __shfl_xor(a1, off);
    a2 += __shfl_xor(a2, off); a3 += __shfl_xor(a3, off);
    ac += __shfl_xor(ac, off);
  }
  __shared__ float r[4][5];
  if ((t & 63) == 0) {
    int w = t >> 6;
    r[w][0] = a0; r[w][1] = a1; r[w][2] = a2; r[w][3] = a3; r[w][4] = ac;
  }
  __syncthreads();
  if (t == 0) {
    float s[5];
    for (int j = 0; j < 5; j++) s[j] = r[0][j] + r[1][j] + r[2][j] + r[3][j];
    float* pu = PU + (v * 16 + h) * 4;
    pu[0] = 0.125f * s[0]; pu[1] = 0.125f * s[1];
    pu[2] = 0.125f * s[2]; pu[3] = 0.125f * s[3];
    C0[v * 16 + h] = 0.125f * (s[4] + qb[h]);
  }
}

// PW[(v*1024+col)*4+p] = sum_d Wv[col,d]*pw[v,d,p]
// CV[v*1024+col]       = sum_d Wv[col,d]*(pb+ve)[v,d] + bv[col]    (grid 5120)
__global__ __launch_bounds__(256) void k_pw(
    const float* __restrict__ wv, const float* __restrict__ bv,
    const float* __restrict__ pw, const float* __restrict__ pb,
    const float* __restrict__ ve, float* __restrict__ PW,
    float* __restrict__ CV) {
  int v = blockIdx.x >> 10, col = blockIdx.x & 1023;
  int t = threadIdx.x;
  const float* wr = wv + (size_t)col * 1024;
  float4 w4 = *(const float4*)(wr + t * 4);
  float a0 = 0, a1 = 0, a2 = 0, a3 = 0, ac = 0;
#pragma unroll
  for (int j = 0; j < 4; j++) {
    int d = t * 4 + j;
    float wj = (j == 0) ? w4.x : (j == 1) ? w4.y : (j == 2) ? w4.z : w4.w;
    const float* p4 = pw + ((size_t)v * 1024 + d) * 4;
    a0 += wj * p4[0]; a1 += wj * p4[1]; a2 += wj * p4[2]; a3 += wj * p4[3];
    ac += wj * (pb[v * 1024 + d] + ve[v * 1024 + d]);
  }
  for (int off = 1; off < 64; off <<= 1) {
    a0 += __shfl_xor(a0, off); a1 += __shfl_xor(a1, off);
    a2 += __shfl_xor(a2, off); a3 += __shfl_xor(a3, off);
    ac += __shfl_xor(ac, off);
  }
  __shared__ float r[4][5];
  if ((t & 63) == 0) {
    int w = t >> 6;
    r[w][0] = a0; r[w][1] = a1; r[w][2] = a2; r[w][3] = a3; r[w][4] = ac;
  }
  __syncthreads();
  if (t == 0) {
    float s[5];
    for (int j = 0; j < 5; j++) s[j] = r[0][j] + r[1][j] + r[2][j] + r[3][j];
    float* o = PW + ((size_t)(v * 1024 + col)) * 4;
    o[0] = s[0]; o[1] = s[1]; o[2] = s[2]; o[3] = s[3];
    CV[v * 1024 + col] = s[4] + bv[col];
  }
}

// scores s[v][h] = patches[m,v]·PU[v,h] + C0[v,h]; softmax over v
// -> amat[m*80 + h*5 + v]                                          (grid 1024)
__global__ __launch_bounds__(256) void k_scoresm(
    const float* __restrict__ patches, const float* __restrict__ PU,
    const float* __restrict__ C0, float* __restrict__ amat) {
  __shared__ float pat[20];
  __shared__ float sa[16][8];
  int m = blockIdx.x, t = threadIdx.x;
  if (t < 20) pat[t] = patches[m * 20 + t];
  __syncthreads();
  if (t < 80) {
    int v = t / 16, h = t % 16;
    const float* pu = PU + (v * 16 + h) * 4;
    float s = C0[v * 16 + h] + pat[v * 4 + 0] * pu[0] + pat[v * 4 + 1] * pu[1]
            + pat[v * 4 + 2] * pu[2] + pat[v * 4 + 3] * pu[3];
    sa[h][v] = s;
  }
  __syncthreads();
  if (t < 16) {
    float mx = sa[t][0];
    for (int v = 1; v < 5; v++) mx = fmaxf(mx, sa[t][v]);
    float e[5], sum = 0.f;
    for (int v = 0; v < 5; v++) { e[v] = __expf(sa[t][v] - mx); sum += e[v]; }
    float inv = 1.f / sum;
    for (int v = 0; v < 5; v++) amat[m * 80 + t * 5 + v] = e[v] * inv;
  }
}

// agg[m,c] = sum_v amat[m,h(c),v] * (patches[m,v]·PW[v,c] + CV[v,c]) (grid 1024)
__global__ __launch_bounds__(256) void k_agg(
    const float* __restrict__ patches, const float* __restrict__ PW,
    const float* __restrict__ CV, const float* __restrict__ amat,
    float* __restrict__ agg) {
  __shared__ float pat[20];
  __shared__ float am[80];
  int m = blockIdx.x, t = threadIdx.x;
  if (t < 20) pat[t] = patches[m * 20 + t];
  if (t < 80) am[t] = amat[m * 80 + t];
  __syncthreads();
  int c0 = t * 4;
#pragma unroll
  for (int j = 0; j < 4; j++) {
    int c = c0 + j;
    int h = c >> 6;
    float acc = 0.f;
#pragma unroll
    for (int v = 0; v < 5; v++) {
      float4 w4 = *(const float4*)(PW + ((size_t)(v * 1024 + c)) * 4);
      float val = pat[v * 4 + 0] * w4.x + pat[v * 4 + 1] * w4.y
                + pat[v * 4 + 2] * w4.z + pat[v * 4 + 3] * w4.w
                + CV[v * 1024 + c];
      acc += am[h * 5 + v] * val;
    }
    agg[(size_t)m * 1024 + c] = acc;
  }
}

// ---------------------------------------------------------------------------
// Generic fp32 GEMM: C[M][N] = A[M][K] @ W[N][K]^T + bias, epilogues.
// EPI: 0 plain, 1 gelu(exact), 2 +resid, 3 +pos+lt
// ---------------------------------------------------------------------------
template <int EPI>
__global__ __launch_bounds__(256) void k_gemm(
    const float* __restrict__ A, const float* __restrict__ W,
    const float* __restrict__ bias, float* __restrict__ C,
    int M, int N, int K,
    const float* __restrict__ resid,
    const float* __restrict__ pos, const float* __restrict__ ltw,
    const float* __restrict__ ltb, const float* __restrict__ lead) {
  __shared__ float As[16][68];
  __shared__ float Ws[16][68];
  int m0 = blockIdx.y * 64, n0 = blockIdx.x * 64;
  int tid = threadIdx.x;
  int tx = tid & 15, ty = tid >> 4;
  int lr = tid & 63, lk = (tid >> 6) * 4;
  float acc[4][4] = {};
  for (int k0 = 0; k0 < K; k0 += 16) {
    float4 av = *(const float4*)(A + (size_t)(m0 + lr) * K + k0 + lk);
    float4 wv = {0.f, 0.f, 0.f, 0.f};
    if (n0 + lr < N) {
      wv = *(const float4*)(W + (size_t)(n0 + lr) * K + k0 + lk);
    }
    __syncthreads();
    As[lk + 0][lr] = av.x; As[lk + 1][lr] = av.y;
    As[lk + 2][lr] = av.z; As[lk + 3][lr] = av.w;
    Ws[lk + 0][lr] = wv.x; Ws[lk + 1][lr] = wv.y;
    Ws[lk + 2][lr] = wv.z; Ws[lk + 3][lr] = wv.w;
    __syncthreads();
#pragma unroll
    for (int kk = 0; kk < 16; kk++) {
      float4 a = *(const float4*)&As[kk][ty * 4];
      float4 b = *(const float4*)&Ws[kk][tx * 4];
      acc[0][0] += a.x * b.x; acc[0][1] += a.x * b.y; acc[0][2] += a.x * b.z; acc[0][3] += a.x * b.w;
      acc[1][0] += a.y * b.x; acc[1][1] += a.y * b.y; acc[1][2] += a.y * b.z; acc[1][3] += a.y * b.w;
      acc[2][0] += a.z * b.x; acc[2][1] += a.z * b.y; acc[2][2] += a.z * b.z; acc[2][3] += a.z * b.w;
      acc[3][0] += a.w * b.x; acc[3][1] += a.w * b.y; acc[3][2] += a.w * b.z; acc[3][3] += a.w * b.w;
    }
  }
#pragma unroll
  for (int ii = 0; ii < 4; ii++) {
    int m = m0 + ty * 4 + ii;
#pragma unroll
    for (int jj = 0; jj < 4; jj++) {
      int n = n0 + tx * 4 + jj;
      if (n >= N) continue;
      float v = acc[ii][jj] + bias[n];
      if (EPI == 1) v = 0.5f * v * (1.f + erff(v * 0.70710678118f));
      if (EPI == 2) v += resid[(size_t)m * N + n];
      if (EPI == 3) {
        int b = m >> 9, l = m & 511;
        v += pos[(size_t)l * 1024 + n] + ltw[n] * lead[b] + ltb[n];
      }
      C[(size_t)m * N + n] = v;
    }
  }
}

// ---------------------------------------------------------------------------
// LayerNorm over D=1024 (grid M). In-place safe.
// ---------------------------------------------------------------------------
__global__ __launch_bounds__(256) void k_ln(
    const float* __restrict__ src, const float* __restrict__ add,
    const float* __restrict__ g, const float* __restrict__ bb,
    float* __restrict__ dst) {
  __shared__ float red[8];
  int m = blockIdx.x, tid = threadIdx.x;
  float4 x = *(const float4*)(src + (size_t)m * 1024 + tid * 4);
  if (add) {
    float4 a2 = *(const float4*)(add + (size_t)m * 1024 + tid * 4);
    x.x += a2.x; x.y += a2.y; x.z += a2.z; x.w += a2.w;
  }
  float s1 = x.x + x.y + x.z + x.w;
  float s2 = x.x * x.x + x.y * x.y + x.z * x.z + x.w * x.w;
  for (int off = 1; off < 64; off <<= 1) {
    s1 += __shfl_xor(s1, off); s2 += __shfl_xor(s2, off);
  }
  if ((tid & 63) == 0) { red[(tid >> 6) * 2] = s1; red[(tid >> 6) * 2 + 1] = s2; }
  __syncthreads();
  s1 = red[0] + red[2] + red[4] + red[6];
  s2 = red[1] + red[3] + red[5] + red[7];
  float mean = s1 * (1.f / 1024.f);
  float var = s2 * (1.f / 1024.f) - mean * mean;
  float rstd = rsqrtf(var + EPSF);
  int c = tid * 4;
  float4 o;
  o.x = (x.x - mean) * rstd * g[c + 0] + bb[c + 0];
  o.y = (x.y - mean) * rstd * g[c + 1] + bb[c + 1];
  o.z = (x.z - mean) * rstd * g[c + 2] + bb[c + 2];
  o.w = (x.w - mean) * rstd * g[c + 3] + bb[c + 3];
  *(float4*)(dst + (size_t)m * 1024 + c) = o;
}

// ---------------------------------------------------------------------------
// Patch attention: per (b,h,ntile16). Two-pass softmax with S in LDS.
// ---------------------------------------------------------------------------
__global__ __launch_bounds__(256) void k_attn(
    const float* __restrict__ qkv, float* __restrict__ o) {
  __shared__ float Q[16][68];
  __shared__ float S[16][516];
  __shared__ float KV[32][68];
  int bid = blockIdx.x;
  int nt = bid & 31, h = (bid >> 5) & 15, b = bid >> 9;
  int tid = threadIdx.x;
  for (int i = tid; i < 16 * 64; i += 256) {
    int r = i >> 6, e = i & 63;
    Q[r][e] = qkv[(size_t)(b * 512 + nt * 16 + r) * 3072 + h * 64 + e];
  }
  __syncthreads();
  int r = tid >> 4, lane = tid & 15;
  for (int kt = 0; kt < 16; kt++) {
    for (int i = tid; i < 32 * 64; i += 256) {
      int rr = i >> 6, e = i & 63;
      KV[rr][e] = qkv[(size_t)(b * 512 + kt * 32 + rr) * 3072 + 1024 + h * 64 + e];
    }
    __syncthreads();
    for (int jj = lane; jj < 32; jj += 16) {
      float acc = 0.f;
#pragma unroll 8
      for (int e = 0; e < 64; e++) acc += Q[r][e] * KV[jj][e];
      S[r][kt * 32 + jj] = acc * 0.125f;
    }
    __syncthreads();
  }
  float mx = -1e30f;
  for (int j = lane; j < 512; j += 16) mx = fmaxf(mx, S[r][j]);
  for (int off = 1; off < 16; off <<= 1) mx = fmaxf(mx, __shfl_xor(mx, off));
  float sum = 0.f;
  for (int j = lane; j < 512; j += 16) {
    float e = __expf(S[r][j] - mx);
    S[r][j] = e; sum += e;
  }
  sum = red16(sum);
  float inv = 1.f / sum;
  int e0 = lane * 4;
  float4 accv = {0.f, 0.f, 0.f, 0.f};
  for (int kt = 0; kt < 16; kt++) {
    __syncthreads();
    for (int i = tid; i < 32 * 64; i += 256) {
      int rr = i >> 6, e = i & 63;
      KV[rr][e] = qkv[(size_t)(b * 512 + kt * 32 + rr) * 3072 + 2048 + h * 64 + e];
    }
    __syncthreads();
#pragma unroll 8
    for (int j = 0; j < 32; j++) {
      float p = S[r][kt * 32 + j] * inv;
      accv.x += p * KV[j][e0 + 0]; accv.y += p * KV[j][e0 + 1];
      accv.z += p * KV[j][e0 + 2]; accv.w += p * KV[j][e0 + 3];
    }
  }
  float* op = o + (size_t)(b * 512 + nt * 16 + r) * 1024 + h * 64 + e0;
  op[0] = accv.x; op[1] = accv.y; op[2] = accv.z; op[3] = accv.w;
}

// ---------------------------------------------------------------------------
// ODE persistent kernel v6: async LDS weight staging (global_load_lds w=16).
// 64 blocks x 1024 thr (16 waves); block owns 16 tokens (full M=16 tile).
// Weight chunk = K=32 x 512 cols = 32 KB; 64 chunks/GEMM double-buffered.
// Wave w owns 4 col-tiles: c = (ct>>1)*512 + w*32 + (ct&1)*16 + col.
// Per chunk per wave: 2 stage instrs (next) + 1 A ds_read + 2 MFMAs.
// Wbuf slot swizzle: s = crel*4 + (q4 ^ ((crel>>1)&3)) keeps B-reads ~2-way.
// y, accr in VGPRs (wave=token epilogue). LDS 128 KB total.
// ---------------------------------------------------------------------------
__device__ __forceinline__ int swz(int m, int c) {
  int g = c >> 3;
  g = (g & ~7) | ((g ^ m) & 7);
  return m * 1024 + g * 8 + (c & 7);
}
__device__ __forceinline__ int swz8(int m, int k) {  // k multiple of 8
  int g = k >> 3;
  g = (g & ~7) | ((g ^ m) & 7);
  return m * 1024 + g * 8;
}

// stage one 32KB chunk (kc, half) of w into wbuf (this wave's share: 2 instrs)
__device__ __forceinline__ void stage_chunk(
    const u16* __restrict__ w, u16* __restrict__ wbuf,
    int kc, int half, int wv, int lane) {
#pragma unroll
  for (int i = 0; i < 2; i++) {
    int s = wv * 128 + i * 64 + lane;       // slot 0..2047
    int crel = s >> 2;
    int c = half * 512 + crel;
    int gp = s & 3;
    int q4 = gp ^ ((crel >> 1) & 3);        // swizzled k-quarter
    const u16* g = w + (size_t)c * 1024 + kc * 32 + q4 * 8;
    u16* l = wbuf + (size_t)(wv * 128 + i * 64) * 8;  // wave-uniform base
    __builtin_amdgcn_global_load_lds(
        (const __attribute__((address_space(1))) uint32_t*)g,
        (__attribute__((address_space(3))) uint32_t*)l, 16, 0, 0);
  }
}

__global__ __launch_bounds__(1024, 4) void k_ode(
    const float* __restrict__ xs, float* __restrict__ out,
    const u16* __restrict__ w1, const float* __restrict__ b1,
    const u16* __restrict__ w2, const float* __restrict__ b2,
    const float* __restrict__ ng, const float* __restrict__ nb,
    const float* __restrict__ lead) {
  __shared__ u16 bufA[16 * 1024];
  __shared__ u16 bufH[16 * 1024];
  __shared__ u16 wbuf[2][16 * 1024];        // 2 x 32KB chunk buffers
  int tid = threadIdx.x;
  int m0 = blockIdx.x * 16;
  int idxb = (int)roundf(lead[m0 >> 9] * 100.0f);
  int wvid = tid >> 6, lane = tid & 63;
  int col = lane & 15, quad = lane >> 4;
  int ec0 = lane * 16;
  float y[16], accr[16];
  {
    const float* yp = xs + (size_t)(m0 + wvid) * 1024 + ec0;
    float* op = out + (size_t)(m0 + wvid) * 1024 + ec0;
#pragma unroll
    for (int j = 0; j < 16; j++) {
      y[j] = yp[j]; op[j] = y[j];
      bufA[swz(wvid, ec0 + j)] = f2b(y[j]);
    }
  }
  __syncthreads();
  const float h6 = RESF / 6.0f;

  for (int s = 0; s < NSTEPS; s++) {
    for (int ph = 0; ph < 4; ph++) {
      int dir = (s * 4 + ph) & 1;  // palindromic chunk order
      // ================= GEMM1: bufH = relu(bufA @ w1^T + b1) ==============
      f32x4 acc[4] = {};
      {
        int cc0 = dir ? 63 : 0;
        stage_chunk(w1, wbuf[0], cc0 >> 1, cc0 & 1, wvid, lane);
        for (int ci = 0; ci < 64; ci++) {
          __syncthreads();  // drains this wave's staging (vmcnt) + syncs
          if (ci < 63) {
            int cn = dir ? 63 - (ci + 1) : (ci + 1);
            stage_chunk(w1, wbuf[(ci + 1) & 1], cn >> 1, cn & 1, wvid, lane);
          }
          int cc = dir ? 63 - ci : ci;
          int kc = cc >> 1, half = cc & 1;
          const u16* wb = wbuf[ci & 1];
          bf16x8 aF = *(const bf16x8*)(bufA + swz8(col, kc * 32 + quad * 8));
#pragma unroll
          for (int j = 0; j < 2; j++) {
            int crel = wvid * 32 + j * 16 + col;
            int slot = crel * 4 + (quad ^ ((crel >> 1) & 3));
            bf16x8 bF = *(const bf16x8*)(wb + slot * 8);
            acc[half * 2 + j] = __builtin_amdgcn_mfma_f32_16x16x32_bf16(
                aF, bF, acc[half * 2 + j], 0, 0, 0);
          }
        }
#pragma unroll
        for (int ct = 0; ct < 4; ct++) {
          int c = (ct >> 1) * 512 + wvid * 32 + (ct & 1) * 16 + col;
          float bv = b1[c];
#pragma unroll
          for (int rr = 0; rr < 4; rr++)
            bufH[swz(quad * 4 + rr, c)] = f2b(fmaxf(acc[ct][rr] + bv, 0.f));
        }
      }
      // ================= GEMM2: z = bufH @ w2^T ============================
      f32x4 acc2[4] = {};
      {
        int cc0 = dir ? 63 : 0;
        stage_chunk(w2, wbuf[0], cc0 >> 1, cc0 & 1, wvid, lane);
        for (int ci = 0; ci < 64; ci++) {
          __syncthreads();  // also guards bufH writes at ci=0
          if (ci < 63) {
            int cn = dir ? 63 - (ci + 1) : (ci + 1);
            stage_chunk(w2, wbuf[(ci + 1) & 1], cn >> 1, cn & 1, wvid, lane);
          }
          int cc = dir ? 63 - ci : ci;
          int kc = cc >> 1, half = cc & 1;
          const u16* wb = wbuf[ci & 1];
          bf16x8 aF = *(const bf16x8*)(bufH + swz8(col, kc * 32 + quad * 8));
#pragma unroll
          for (int j = 0; j < 2; j++) {
            int crel = wvid * 32 + j * 16 + col;
            int slot = crel * 4 + (quad ^ ((crel >> 1) & 3));
            bf16x8 bF = *(const bf16x8*)(wb + slot * 8);
            acc2[half * 2 + j] = __builtin_amdgcn_mfma_f32_16x16x32_bf16(
                aF, bF, acc2[half * 2 + j], 0, 0, 0);
          }
        }
      }
      __syncthreads();  // all waves done reading bufH before overwrite
      // ---- z = acc2 + b2 + resid(bufA) -> bufH ----
#pragma unroll
      for (int ct = 0; ct < 4; ct++) {
        int c = (ct >> 1) * 512 + wvid * 32 + (ct & 1) * 16 + col;
        float bv = b2[c];
#pragma unroll
        for (int rr = 0; rr < 4; rr++) {
          int mr = quad * 4 + rr;
          float z = acc2[ct][rr] + bv + b2f(bufA[swz(mr, c)]);
          bufH[swz(mr, c)] = f2b(z);
        }
      }
      __syncthreads();
      // ---- epilogue: LN (wave = token) + RK4 state update ----
      {
        float z16[16];
        float s1 = 0.f, s2 = 0.f;
#pragma unroll
        for (int j = 0; j < 16; j++) {
          z16[j] = b2f(bufH[swz(wvid, ec0 + j)]);
          s1 += z16[j]; s2 += z16[j] * z16[j];
        }
        for (int off = 1; off < 64; off <<= 1) {
          s1 += __shfl_xor(s1, off); s2 += __shfl_xor(s2, off);
        }
        float mean = s1 * (1.f / 1024.f);
        float var = s2 * (1.f / 1024.f) - mean * mean;
        float rstd = rsqrtf(var + EPSF);
        float cf = (ph < 2) ? 0.5f * RESF : RESF;
#pragma unroll
        for (int j = 0; j < 16; j++) {
          int c = ec0 + j;
          float k = (z16[j] - mean) * rstd * ng[c] + nb[c];
          float nv;
          if (ph == 0)      { accr[j] = k;        nv = y[j] + cf * k; }
          else if (ph < 3)  { accr[j] += 2.f * k; nv = y[j] + cf * k; }
          else              { y[j] += h6 * (accr[j] + k); nv = y[j]; }
          bufA[swz(wvid, c)] = f2b(nv);
        }
        if (ph == 3 && (s + 1) == idxb) {
          float* op = out + (size_t)(m0 + wvid) * 1024 + ec0;
#pragma unroll
          for (int j = 0; j < 16; j++) op[j] = y[j];
        }
      }
      __syncthreads();
    }
  }
}

// ---------------------------------------------------------------------------
// Unpatchify: y3[m][p*10+q*5+c] -> out[b][c][hh*2+p][ww*2+q], FLOAT32
// ---------------------------------------------------------------------------
__global__ __launch_bounds__(256) void k_unpatch(
    const float* __restrict__ y3, float* __restrict__ outp) {
  int o = blockIdx.x * 256 + threadIdx.x;
  if (o >= 20480) return;
  int b = o / 10240;
  int c = (o / 2048) % 5;
  int hrow = (o / 64) % 32;
  int wcol = o % 64;
  int hh = hrow >> 1, p = hrow & 1, ww = wcol >> 1, q = wcol & 1;
  int m2 = b * 512 + hh * 32 + ww;
  int colj = p * 10 + q * 5 + c;
  outp[o] = y3[(size_t)m2 * 20 + colj];
}

// ===========================================================================
extern "C" void kernel_launch(void* const* d_in, const int* in_sizes, int n_in,
                              void* d_out, int out_size, void* d_ws, size_t ws_size,
                              hipStream_t stream) {
  const float* x         = (const float*)d_in[0];
  const float* lead      = (const float*)d_in[1];
  const float* patch_w   = (const float*)d_in[2];
  const float* patch_b   = (const float*)d_in[3];
  const float* var_embed = (const float*)d_in[4];
  const float* var_query = (const float*)d_in[5];
  const float* agg_in_w  = (const float*)d_in[6];
  const float* agg_in_b  = (const float*)d_in[7];
  const float* agg_out_w = (const float*)d_in[8];
  const float* agg_out_b = (const float*)d_in[9];
  const float* pos_embed = (const float*)d_in[10];
  const float* lt_w      = (const float*)d_in[11];
  const float* lt_b      = (const float*)d_in[12];
  const float* blk_qkv_w = (const float*)d_in[13];
  const float* blk_qkv_b = (const float*)d_in[14];
  const float* blk_out_w = (const float*)d_in[15];
  const float* blk_out_b = (const float*)d_in[16];
  const float* blk_n1_g  = (const float*)d_in[17];
  const float* blk_n1_b  = (const float*)d_in[18];
  const float* blk_n2_g  = (const float*)d_in[19];
  const float* blk_n2_b  = (const float*)d_in[20];
  const float* ode_w1    = (const float*)d_in[21];
  const float* ode_b1    = (const float*)d_in[22];
  const float* ode_w2    = (const float*)d_in[23];
  const float* ode_b2    = (const float*)d_in[24];
  const float* ode_ng    = (const float*)d_in[25];
  const float* ode_nb    = (const float*)d_in[26];
  const float* norm_g    = (const float*)d_in[27];
  const float* norm_b    = (const float*)d_in[28];
  const float* h1_w      = (const float*)d_in[29];
  const float* h1_b      = (const float*)d_in[30];
  const float* h2_w      = (const float*)d_in[31];
  const float* h2_b      = (const float*)d_in[32];
  const float* hf_w      = (const float*)d_in[33];
  const float* hf_b      = (const float*)d_in[34];
  (void)in_sizes; (void)n_in; (void)out_size; (void)ws_size;

  float* ws = (float*)d_ws;
  float* patches = ws + 0;         // 20480
  float* qvec    = ws + 20480;     // 1024
  float* qb      = ws + 21504;     // 256 (16 used)
  float* u       = ws + 21760;     // 16384
  float* PU      = ws + 38144;     // 320
  float* C0      = ws + 38464;     // 80 (pad to 40960)
  float* amat    = ws + 40960;     // 81920
  float* PW      = ws + 122880;    // 20480
  float* CV      = ws + 143360;    // 5120  (end 148480 < 3145728)
  float* agg     = ws + 3145728;   // 1048576 (attno slot; dead by then)
  float* qkv   = ws + 0;           // 3145728
  float* attno = ws + 3145728;     // 1048576
  float* t1    = ws + 4194304;     // 1048576
  float* odeo  = ws + 5242880;     // 1048576
  float* xs    = ws + 6291456;     // 1048576
  u16*   w16a  = (u16*)(ws + 7340032);  // per-depth w1 (bf16)
  u16*   w16b  = (u16*)(ws + 7864320);  // per-depth w2 (bf16)
  float* y1 = ws + 0;
  float* y2 = ws + 1048576;
  float* y3 = ws + 2097152;        // 20480

  // ---- stage 1 ----
  k_patches<<<dim3(80), dim3(256), 0, stream>>>(x, patches);
  k_qvec<<<dim3(64), dim3(256), 0, stream>>>(var_query, agg_in_w, agg_in_b, qvec);
  k_qb<<<dim3(1), dim3(256), 0, stream>>>(qvec, agg_in_b + 1024, qb);
  k_u<<<dim3(64), dim3(256), 0, stream>>>(qvec, agg_in_w + (size_t)1024 * 1024, u);
  k_pu<<<dim3(80), dim3(256), 0, stream>>>(patch_w, patch_b, var_embed, u, qb, PU, C0);
  k_pw<<<dim3(5120), dim3(256), 0, stream>>>(
      agg_in_w + (size_t)2048 * 1024, agg_in_b + 2048, patch_w, patch_b,
      var_embed, PW, CV);
  k_scoresm<<<dim3(1024), dim3(256), 0, stream>>>(patches, PU, C0, amat);
  k_agg<<<dim3(1024), dim3(256), 0, stream>>>(patches, PW, CV, amat, agg);
  k_gemm<3><<<dim3(16, 16), dim3(256), 0, stream>>>(
      agg, agg_out_w, agg_out_b, xs, 1024, 1024, 1024,
      nullptr, pos_embed, lt_w, lt_b, lead);

  // ---- transformer blocks ----
  for (int i = 0; i < 2; i++) {
    k_gemm<0><<<dim3(48, 16), dim3(256), 0, stream>>>(
        xs, blk_qkv_w + (size_t)i * 3072 * 1024, blk_qkv_b + i * 3072, qkv,
        1024, 3072, 1024, nullptr, nullptr, nullptr, nullptr, nullptr);
    k_attn<<<dim3(1024), dim3(256), 0, stream>>>(qkv, attno);
    k_gemm<2><<<dim3(16, 16), dim3(256), 0, stream>>>(
        attno, blk_out_w + (size_t)i * 1048576, blk_out_b + i * 1024, t1,
        1024, 1024, 1024, xs, nullptr, nullptr, nullptr, nullptr);
    k_ln<<<dim3(1024), dim3(256), 0, stream>>>(
        t1, (const float*)nullptr, blk_n1_g + i * 1024, blk_n1_b + i * 1024, xs);
    k_cvt<<<dim3(4096), dim3(256), 0, stream>>>(ode_w1 + (size_t)i * 1048576, w16a, 1048576);
    k_cvt<<<dim3(4096), dim3(256), 0, stream>>>(ode_w2 + (size_t)i * 1048576, w16b, 1048576);
    k_ode<<<dim3(64), dim3(1024), 0, stream>>>(
        xs, odeo, w16a, ode_b1 + i * 1024, w16b, ode_b2 + i * 1024,
        ode_ng + i * 1024, ode_nb + i * 1024, lead);
    k_ln<<<dim3(1024), dim3(256), 0, stream>>>(
        xs, odeo, blk_n2_g + i * 1024, blk_n2_b + i * 1024, xs);
  }

  // ---- head ----
  k_ln<<<dim3(1024), dim3(256), 0, stream>>>(
      xs, (const float*)nullptr, norm_g, norm_b, xs);
  k_gemm<1><<<dim3(16, 16), dim3(256), 0, stream>>>(
      xs, h1_w, h1_b, y1, 1024, 1024, 1024, nullptr, nullptr, nullptr, nullptr, nullptr);
  k_gemm<1><<<dim3(16, 16), dim3(256), 0, stream>>>(
      y1, h2_w, h2_b, y2, 1024, 1024, 1024, nullptr, nullptr, nullptr, nullptr, nullptr);
  k_gemm<0><<<dim3(1, 16), dim3(256), 0, stream>>>(
      y2, hf_w, hf_b, y3, 1024, 20, 1024, nullptr, nullptr, nullptr, nullptr, nullptr);
  k_unpatch<<<dim3(80), dim3(256), 0, stream>>>(y3, (float*)d_out);
}

// Round 11
// 7347.780 us; speedup vs baseline: 2.7183x; 1.3186x over previous
//
#include <hip/hip_runtime.h>
#include <stdint.h>

// ============================================================================
// ConViTCast: B=2 V=5 H=32 W=64 P=2 D=1024 NH=16 hd=64 DEPTH=2 L=512 BL=1024
// Inputs f32, output f32. Round 11: k_ode v7 — barrier-free k-loop.
// R10 evidence: 128 __syncthreads/phase each draining vmcnt(0) -> serial
// chunk staging (0.82us x 128 = 105us/phase vs 31us L2-BW floor).
// v7: per-wave weight staging (wave owns 64 cols) into per-wave 3x2KB LDS
// ring, synced with per-wave s_waitcnt vmcnt(N) (stage-ahead-2). Barriers
// only at GEMM boundaries (4/phase). Waves drift -> latency overlapped by
// 4 waves/SIMD TLP. LDS = 32K bufA + 32K bufH + 96K wbuf = 160KB exact.
// ============================================================================

#define NSTEPS 10
#define RESF 0.01f
#define EPSF 1e-5f

typedef unsigned short u16;
typedef __attribute__((ext_vector_type(8))) short bf16x8;
typedef __attribute__((ext_vector_type(4))) float f32x4;

// s_waitcnt vmcnt(N), ignore exp/lgkm (gfx9 encoding: vm[3:0]|[15:14], exp=7, lgkm=15)
#define VMCNT(N) __builtin_amdgcn_s_waitcnt(0x0F70 | ((N) & 0xF) | ((((N) >> 4) & 0x3) << 14))

__device__ __forceinline__ float b2f(u16 u) {
  return __uint_as_float(((uint32_t)u) << 16);
}
__device__ __forceinline__ u16 f2b(float f) {
  uint32_t x = __float_as_uint(f);
  uint32_t r = x + 0x7fffu + ((x >> 16) & 1u);  // round-to-nearest-even
  return (u16)(r >> 16);
}
__device__ __forceinline__ float red16(float v) {
  v += __shfl_xor(v, 1); v += __shfl_xor(v, 2);
  v += __shfl_xor(v, 4); v += __shfl_xor(v, 8);
  return v;
}

// f32 -> bf16 conversion (for ODE weights)
__global__ __launch_bounds__(256) void k_cvt(
    const float* __restrict__ in, u16* __restrict__ out16, int n) {
  int i = blockIdx.x * 256 + threadIdx.x;
  if (i < n) out16[i] = f2b(in[i]);
}

// ---------------------------------------------------------------------------
// Extract patches[m*20 + v*4 + p] from x[b,v,h,w]; m=b*512+l, l=hh*32+ww
// ---------------------------------------------------------------------------
__global__ __launch_bounds__(256) void k_patches(
    const float* __restrict__ x, float* __restrict__ patches) {
  int i = blockIdx.x * 256 + threadIdx.x;  // grid 80*256 = 20480
  int m = i / 20, r = i % 20;
  int v = r >> 2, p = r & 3;
  int b = m >> 9, l = m & 511;
  int hh = l >> 5, ww = l & 31;
  int pr = p >> 1, pc = p & 1;
  patches[i] = x[((size_t)(b * 5 + v) * 32 + hh * 2 + pr) * 64 + ww * 2 + pc];
}

// qvec = var_query @ Wq^T + bq   (grid 64)
__global__ __launch_bounds__(256) void k_qvec(
    const float* __restrict__ vq, const float* __restrict__ w,
    const float* __restrict__ bias, float* __restrict__ qvec) {
  int dq = blockIdx.x * 16 + (threadIdx.x >> 4);
  int lane = threadIdx.x & 15;
  float p = 0.f;
  for (int j = 0; j < 64; j++) {
    int d = lane + 16 * j;
    p += vq[d] * w[(size_t)dq * 1024 + d];
  }
  p = red16(p);
  if (lane == 0) qvec[dq] = p + bias[dq];
}

// qb[h] = sum_e qvec[h*64+e]*bk[h*64+e]   (grid 1)
__global__ __launch_bounds__(256) void k_qb(
    const float* __restrict__ qvec, const float* __restrict__ bk,
    float* __restrict__ qb) {
  int h = threadIdx.x >> 4, lane = threadIdx.x & 15;
  float p = 0.f;
  for (int e = lane; e < 64; e += 16) p += qvec[h * 64 + e] * bk[h * 64 + e];
  p = red16(p);
  if (lane == 0) qb[h] = p;
}

// u[h][d] = sum_e qvec[h*64+e] * Wk[h*64+e][d]   (grid 64)
__global__ __launch_bounds__(256) void k_u(
    const float* __restrict__ qvec, const float* __restrict__ wk,
    float* __restrict__ u) {
  int d = blockIdx.x * 16 + (threadIdx.x & 15);
  int h = threadIdx.x >> 4;
  float acc = 0.f;
  for (int e = 0; e < 64; e++)
    acc += qvec[h * 64 + e] * wk[(size_t)(h * 64 + e) * 1024 + d];
  u[h * 1024 + d] = acc;
}

// PU[(v*16+h)*4+p] = 0.125*sum_d pw[v,d,p]*u[h,d]
// C0[v*16+h]       = 0.125*(sum_d (pb+ve)[v,d]*u[h,d] + qb[h])     (grid 80)
__global__ __launch_bounds__(256) void k_pu(
    const float* __restrict__ pw, const float* __restrict__ pb,
    const float* __restrict__ ve, const float* __restrict__ u,
    const float* __restrict__ qb, float* __restrict__ PU,
    float* __restrict__ C0) {
  int v = blockIdx.x / 16, h = blockIdx.x % 16;
  int t = threadIdx.x;
  float a0 = 0, a1 = 0, a2 = 0, a3 = 0, ac = 0;
  for (int d = t; d < 1024; d += 256) {
    float uu = u[h * 1024 + d];
    const float* p4 = pw + ((size_t)v * 1024 + d) * 4;
    a0 += p4[0] * uu; a1 += p4[1] * uu; a2 += p4[2] * uu; a3 += p4[3] * uu;
    ac += (pb[v * 1024 + d] + ve[v * 1024 + d]) * uu;
  }
  for (int off = 1; off < 64; off <<= 1) {
    a0 += __shfl_xor(a0, off); a1 += __shfl_xor(a1, off);
    a2 += __shfl_xor(a2, off); a3 += __shfl_xor(a3, off);
    ac += __shfl_xor(ac, off);
  }
  __shared__ float r[4][5];
  if ((t & 63) == 0) {
    int w = t >> 6;
    r[w][0] = a0; r[w][1] = a1; r[w][2] = a2; r[w][3] = a3; r[w][4] = ac;
  }
  __syncthreads();
  if (t == 0) {
    float s[5];
    for (int j = 0; j < 5; j++) s[j] = r[0][j] + r[1][j] + r[2][j] + r[3][j];
    float* pu = PU + (v * 16 + h) * 4;
    pu[0] = 0.125f * s[0]; pu[1] = 0.125f * s[1];
    pu[2] = 0.125f * s[2]; pu[3] = 0.125f * s[3];
    C0[v * 16 + h] = 0.125f * (s[4] + qb[h]);
  }
}

// PW[(v*1024+col)*4+p] = sum_d Wv[col,d]*pw[v,d,p]
// CV[v*1024+col]       = sum_d Wv[col,d]*(pb+ve)[v,d] + bv[col]    (grid 5120)
__global__ __launch_bounds__(256) void k_pw(
    const float* __restrict__ wv, const float* __restrict__ bv,
    const float* __restrict__ pw, const float* __restrict__ pb,
    const float* __restrict__ ve, float* __restrict__ PW,
    float* __restrict__ CV) {
  int v = blockIdx.x >> 10, col = blockIdx.x & 1023;
  int t = threadIdx.x;
  const float* wr = wv + (size_t)col * 1024;
  float4 w4 = *(const float4*)(wr + t * 4);
  float a0 = 0, a1 = 0, a2 = 0, a3 = 0, ac = 0;
#pragma unroll
  for (int j = 0; j < 4; j++) {
    int d = t * 4 + j;
    float wj = (j == 0) ? w4.x : (j == 1) ? w4.y : (j == 2) ? w4.z : w4.w;
    const float* p4 = pw + ((size_t)v * 1024 + d) * 4;
    a0 += wj * p4[0]; a1 += wj * p4[1]; a2 += wj * p4[2]; a3 += wj * p4[3];
    ac += wj * (pb[v * 1024 + d] + ve[v * 1024 + d]);
  }
  for (int off = 1; off < 64; off <<= 1) {
    a0 += __shfl_xor(a0, off); a1 += __shfl_xor(a1, off);
    a2 += __shfl_xor(a2, off); a3 += __shfl_xor(a3, off);
    ac += __shfl_xor(ac, off);
  }
  __shared__ float r[4][5];
  if ((t & 63) == 0) {
    int w = t >> 6;
    r[w][0] = a0; r[w][1] = a1; r[w][2] = a2; r[w][3] = a3; r[w][4] = ac;
  }
  __syncthreads();
  if (t == 0) {
    float s[5];
    for (int j = 0; j < 5; j++) s[j] = r[0][j] + r[1][j] + r[2][j] + r[3][j];
    float* o = PW + ((size_t)(v * 1024 + col)) * 4;
    o[0] = s[0]; o[1] = s[1]; o[2] = s[2]; o[3] = s[3];
    CV[v * 1024 + col] = s[4] + bv[col];
  }
}

// scores s[v][h] = patches[m,v]·PU[v,h] + C0[v,h]; softmax over v
// -> amat[m*80 + h*5 + v]                                          (grid 1024)
__global__ __launch_bounds__(256) void k_scoresm(
    const float* __restrict__ patches, const float* __restrict__ PU,
    const float* __restrict__ C0, float* __restrict__ amat) {
  __shared__ float pat[20];
  __shared__ float sa[16][8];
  int m = blockIdx.x, t = threadIdx.x;
  if (t < 20) pat[t] = patches[m * 20 + t];
  __syncthreads();
  if (t < 80) {
    int v = t / 16, h = t % 16;
    const float* pu = PU + (v * 16 + h) * 4;
    float s = C0[v * 16 + h] + pat[v * 4 + 0] * pu[0] + pat[v * 4 + 1] * pu[1]
            + pat[v * 4 + 2] * pu[2] + pat[v * 4 + 3] * pu[3];
    sa[h][v] = s;
  }
  __syncthreads();
  if (t < 16) {
    float mx = sa[t][0];
    for (int v = 1; v < 5; v++) mx = fmaxf(mx, sa[t][v]);
    float e[5], sum = 0.f;
    for (int v = 0; v < 5; v++) { e[v] = __expf(sa[t][v] - mx); sum += e[v]; }
    float inv = 1.f / sum;
    for (int v = 0; v < 5; v++) amat[m * 80 + t * 5 + v] = e[v] * inv;
  }
}

// agg[m,c] = sum_v amat[m,h(c),v] * (patches[m,v]·PW[v,c] + CV[v,c]) (grid 1024)
__global__ __launch_bounds__(256) void k_agg(
    const float* __restrict__ patches, const float* __restrict__ PW,
    const float* __restrict__ CV, const float* __restrict__ amat,
    float* __restrict__ agg) {
  __shared__ float pat[20];
  __shared__ float am[80];
  int m = blockIdx.x, t = threadIdx.x;
  if (t < 20) pat[t] = patches[m * 20 + t];
  if (t < 80) am[t] = amat[m * 80 + t];
  __syncthreads();
  int c0 = t * 4;
#pragma unroll
  for (int j = 0; j < 4; j++) {
    int c = c0 + j;
    int h = c >> 6;
    float acc = 0.f;
#pragma unroll
    for (int v = 0; v < 5; v++) {
      float4 w4 = *(const float4*)(PW + ((size_t)(v * 1024 + c)) * 4);
      float val = pat[v * 4 + 0] * w4.x + pat[v * 4 + 1] * w4.y
                + pat[v * 4 + 2] * w4.z + pat[v * 4 + 3] * w4.w
                + CV[v * 1024 + c];
      acc += am[h * 5 + v] * val;
    }
    agg[(size_t)m * 1024 + c] = acc;
  }
}

// ---------------------------------------------------------------------------
// Generic fp32 GEMM: C[M][N] = A[M][K] @ W[N][K]^T + bias, epilogues.
// EPI: 0 plain, 1 gelu(exact), 2 +resid, 3 +pos+lt
// ---------------------------------------------------------------------------
template <int EPI>
__global__ __launch_bounds__(256) void k_gemm(
    const float* __restrict__ A, const float* __restrict__ W,
    const float* __restrict__ bias, float* __restrict__ C,
    int M, int N, int K,
    const float* __restrict__ resid,
    const float* __restrict__ pos, const float* __restrict__ ltw,
    const float* __restrict__ ltb, const float* __restrict__ lead) {
  __shared__ float As[16][68];
  __shared__ float Ws[16][68];
  int m0 = blockIdx.y * 64, n0 = blockIdx.x * 64;
  int tid = threadIdx.x;
  int tx = tid & 15, ty = tid >> 4;
  int lr = tid & 63, lk = (tid >> 6) * 4;
  float acc[4][4] = {};
  for (int k0 = 0; k0 < K; k0 += 16) {
    float4 av = *(const float4*)(A + (size_t)(m0 + lr) * K + k0 + lk);
    float4 wv = {0.f, 0.f, 0.f, 0.f};
    if (n0 + lr < N) {
      wv = *(const float4*)(W + (size_t)(n0 + lr) * K + k0 + lk);
    }
    __syncthreads();
    As[lk + 0][lr] = av.x; As[lk + 1][lr] = av.y;
    As[lk + 2][lr] = av.z; As[lk + 3][lr] = av.w;
    Ws[lk + 0][lr] = wv.x; Ws[lk + 1][lr] = wv.y;
    Ws[lk + 2][lr] = wv.z; Ws[lk + 3][lr] = wv.w;
    __syncthreads();
#pragma unroll
    for (int kk = 0; kk < 16; kk++) {
      float4 a = *(const float4*)&As[kk][ty * 4];
      float4 b = *(const float4*)&Ws[kk][tx * 4];
      acc[0][0] += a.x * b.x; acc[0][1] += a.x * b.y; acc[0][2] += a.x * b.z; acc[0][3] += a.x * b.w;
      acc[1][0] += a.y * b.x; acc[1][1] += a.y * b.y; acc[1][2] += a.y * b.z; acc[1][3] += a.y * b.w;
      acc[2][0] += a.z * b.x; acc[2][1] += a.z * b.y; acc[2][2] += a.z * b.z; acc[2][3] += a.z * b.w;
      acc[3][0] += a.w * b.x; acc[3][1] += a.w * b.y; acc[3][2] += a.w * b.z; acc[3][3] += a.w * b.w;
    }
  }
#pragma unroll
  for (int ii = 0; ii < 4; ii++) {
    int m = m0 + ty * 4 + ii;
#pragma unroll
    for (int jj = 0; jj < 4; jj++) {
      int n = n0 + tx * 4 + jj;
      if (n >= N) continue;
      float v = acc[ii][jj] + bias[n];
      if (EPI == 1) v = 0.5f * v * (1.f + erff(v * 0.70710678118f));
      if (EPI == 2) v += resid[(size_t)m * N + n];
      if (EPI == 3) {
        int b = m >> 9, l = m & 511;
        v += pos[(size_t)l * 1024 + n] + ltw[n] * lead[b] + ltb[n];
      }
      C[(size_t)m * N + n] = v;
    }
  }
}

// ---------------------------------------------------------------------------
// LayerNorm over D=1024 (grid M). In-place safe.
// ---------------------------------------------------------------------------
__global__ __launch_bounds__(256) void k_ln(
    const float* __restrict__ src, const float* __restrict__ add,
    const float* __restrict__ g, const float* __restrict__ bb,
    float* __restrict__ dst) {
  __shared__ float red[8];
  int m = blockIdx.x, tid = threadIdx.x;
  float4 x = *(const float4*)(src + (size_t)m * 1024 + tid * 4);
  if (add) {
    float4 a2 = *(const float4*)(add + (size_t)m * 1024 + tid * 4);
    x.x += a2.x; x.y += a2.y; x.z += a2.z; x.w += a2.w;
  }
  float s1 = x.x + x.y + x.z + x.w;
  float s2 = x.x * x.x + x.y * x.y + x.z * x.z + x.w * x.w;
  for (int off = 1; off < 64; off <<= 1) {
    s1 += __shfl_xor(s1, off); s2 += __shfl_xor(s2, off);
  }
  if ((tid & 63) == 0) { red[(tid >> 6) * 2] = s1; red[(tid >> 6) * 2 + 1] = s2; }
  __syncthreads();
  s1 = red[0] + red[2] + red[4] + red[6];
  s2 = red[1] + red[3] + red[5] + red[7];
  float mean = s1 * (1.f / 1024.f);
  float var = s2 * (1.f / 1024.f) - mean * mean;
  float rstd = rsqrtf(var + EPSF);
  int c = tid * 4;
  float4 o;
  o.x = (x.x - mean) * rstd * g[c + 0] + bb[c + 0];
  o.y = (x.y - mean) * rstd * g[c + 1] + bb[c + 1];
  o.z = (x.z - mean) * rstd * g[c + 2] + bb[c + 2];
  o.w = (x.w - mean) * rstd * g[c + 3] + bb[c + 3];
  *(float4*)(dst + (size_t)m * 1024 + c) = o;
}

// ---------------------------------------------------------------------------
// Patch attention: per (b,h,ntile16). Two-pass softmax with S in LDS.
// ---------------------------------------------------------------------------
__global__ __launch_bounds__(256) void k_attn(
    const float* __restrict__ qkv, float* __restrict__ o) {
  __shared__ float Q[16][68];
  __shared__ float S[16][516];
  __shared__ float KV[32][68];
  int bid = blockIdx.x;
  int nt = bid & 31, h = (bid >> 5) & 15, b = bid >> 9;
  int tid = threadIdx.x;
  for (int i = tid; i < 16 * 64; i += 256) {
    int r = i >> 6, e = i & 63;
    Q[r][e] = qkv[(size_t)(b * 512 + nt * 16 + r) * 3072 + h * 64 + e];
  }
  __syncthreads();
  int r = tid >> 4, lane = tid & 15;
  for (int kt = 0; kt < 16; kt++) {
    for (int i = tid; i < 32 * 64; i += 256) {
      int rr = i >> 6, e = i & 63;
      KV[rr][e] = qkv[(size_t)(b * 512 + kt * 32 + rr) * 3072 + 1024 + h * 64 + e];
    }
    __syncthreads();
    for (int jj = lane; jj < 32; jj += 16) {
      float acc = 0.f;
#pragma unroll 8
      for (int e = 0; e < 64; e++) acc += Q[r][e] * KV[jj][e];
      S[r][kt * 32 + jj] = acc * 0.125f;
    }
    __syncthreads();
  }
  float mx = -1e30f;
  for (int j = lane; j < 512; j += 16) mx = fmaxf(mx, S[r][j]);
  for (int off = 1; off < 16; off <<= 1) mx = fmaxf(mx, __shfl_xor(mx, off));
  float sum = 0.f;
  for (int j = lane; j < 512; j += 16) {
    float e = __expf(S[r][j] - mx);
    S[r][j] = e; sum += e;
  }
  sum = red16(sum);
  float inv = 1.f / sum;
  int e0 = lane * 4;
  float4 accv = {0.f, 0.f, 0.f, 0.f};
  for (int kt = 0; kt < 16; kt++) {
    __syncthreads();
    for (int i = tid; i < 32 * 64; i += 256) {
      int rr = i >> 6, e = i & 63;
      KV[rr][e] = qkv[(size_t)(b * 512 + kt * 32 + rr) * 3072 + 2048 + h * 64 + e];
    }
    __syncthreads();
#pragma unroll 8
    for (int j = 0; j < 32; j++) {
      float p = S[r][kt * 32 + j] * inv;
      accv.x += p * KV[j][e0 + 0]; accv.y += p * KV[j][e0 + 1];
      accv.z += p * KV[j][e0 + 2]; accv.w += p * KV[j][e0 + 3];
    }
  }
  float* op = o + (size_t)(b * 512 + nt * 16 + r) * 1024 + h * 64 + e0;
  op[0] = accv.x; op[1] = accv.y; op[2] = accv.z; op[3] = accv.w;
}

// ---------------------------------------------------------------------------
// ODE persistent kernel v7: per-wave staging, barrier-free k-loop.
// 64 blocks x 1024 thr (16 waves); block owns 16 tokens (M=16 tile).
// Wave w owns cols [w*64, w*64+64) = 4 tiles. Chunk = 2 tiles x k32 = 2KB
// (2 global_load_lds w=16 instrs). Per-wave ring of 3 chunks; stage-ahead-2;
// sync via per-wave s_waitcnt vmcnt(2) (tail peeled vmcnt(0)).
// LDS: bufA 32K + bufH 32K + wbuf 96K = 160KB. y/accr in VGPRs.
// ---------------------------------------------------------------------------
__device__ __forceinline__ int swz(int m, int c) {
  int g = c >> 3;
  g = (g & ~7) | ((g ^ m) & 7);
  return m * 1024 + g * 8 + (c & 7);
}
__device__ __forceinline__ int swz8(int m, int k) {  // k multiple of 8
  int g = k >> 3;
  g = (g & ~7) | ((g ^ m) & 7);
  return m * 1024 + g * 8;
}

// stage one 2KB chunk (tile pair at colbase, k-step kc) into dst (per-wave)
__device__ __forceinline__ void ode_stage(
    const u16* __restrict__ w, u16* __restrict__ dst,
    int colbase, int kc, int scl, int sqg) {
  const u16* g0 = w + (size_t)(colbase + scl) * 1024 + kc * 32 + sqg * 8;
  __builtin_amdgcn_global_load_lds(
      (const __attribute__((address_space(1))) uint32_t*)g0,
      (__attribute__((address_space(3))) uint32_t*)dst, 16, 0, 0);
  const u16* g1 = g0 + 16 * 1024;
  __builtin_amdgcn_global_load_lds(
      (const __attribute__((address_space(1))) uint32_t*)g1,
      (__attribute__((address_space(3))) uint32_t*)(dst + 512), 16, 0, 0);
}

__global__ __launch_bounds__(1024, 4) void k_ode(
    const float* __restrict__ xs, float* __restrict__ out,
    const u16* __restrict__ w1, const float* __restrict__ b1,
    const u16* __restrict__ w2, const float* __restrict__ b2,
    const float* __restrict__ ng, const float* __restrict__ nb,
    const float* __restrict__ lead) {
  __shared__ u16 bufA[16 * 1024];
  __shared__ u16 bufH[16 * 1024];
  __shared__ u16 wbuf[16][3][1024];  // per-wave 3-chunk ring (2KB chunks)
  int tid = threadIdx.x;
  int m0 = blockIdx.x * 16;
  int idxb = (int)roundf(lead[m0 >> 9] * 100.0f);
  int wvid = tid >> 6, lane = tid & 63;
  int col = lane & 15, quad = lane >> 4;
  int ec0 = lane * 16;
  int cw = wvid * 64;                        // wave's column base
  int scl = lane >> 2;                       // staged col-local (0..15)
  int sqg = (lane & 3) ^ (scl & 3);          // staged k-quarter (swizzled)
  int rslot = col * 4 + (quad ^ (col & 3));  // read slot within tile
  u16* wbW = &wbuf[wvid][0][0];
  float y[16], accr[16];
  {
    const float* yp = xs + (size_t)(m0 + wvid) * 1024 + ec0;
    float* op = out + (size_t)(m0 + wvid) * 1024 + ec0;
#pragma unroll
    for (int j = 0; j < 16; j++) {
      y[j] = yp[j]; op[j] = y[j];
      bufA[swz(wvid, ec0 + j)] = f2b(y[j]);
    }
  }
  __syncthreads();
  const float h6 = RESF / 6.0f;

  for (int s = 0; s < NSTEPS; s++) {
    for (int ph = 0; ph < 4; ph++) {
      int dir = (s * 4 + ph) & 1;  // palindromic chunk order
      // ================= GEMM1: bufH = relu(bufA @ w1^T + b1) ==============
      f32x4 acc[4] = {};
      {
        int c0 = dir ? 63 : 0, c1 = dir ? 62 : 1;
        ode_stage(w1, wbW, cw + (c0 >> 5) * 32, c0 & 31, scl, sqg);
        ode_stage(w1, wbW + 1024, cw + (c1 >> 5) * 32, c1 & 31, scl, sqg);
        for (int ci = 0; ci < 62; ci++) {
          VMCNT(2);
          int cc = dir ? 63 - ci : ci;
          int g = cc >> 5, kc = cc & 31;
          const u16* wb = wbW + (ci % 3) * 1024;
          bf16x8 aF = *(const bf16x8*)(bufA + swz8(col, kc * 32 + quad * 8));
          bf16x8 f0 = *(const bf16x8*)(wb + rslot * 8);
          bf16x8 f1 = *(const bf16x8*)(wb + 512 + rslot * 8);
          acc[g * 2 + 0] = __builtin_amdgcn_mfma_f32_16x16x32_bf16(aF, f0, acc[g * 2 + 0], 0, 0, 0);
          acc[g * 2 + 1] = __builtin_amdgcn_mfma_f32_16x16x32_bf16(aF, f1, acc[g * 2 + 1], 0, 0, 0);
          int cn = dir ? 63 - (ci + 2) : (ci + 2);
          ode_stage(w1, wbW + ((ci + 2) % 3) * 1024, cw + (cn >> 5) * 32, cn & 31, scl, sqg);
        }
#pragma unroll
        for (int ci = 62; ci < 64; ci++) {
          if (ci == 62) { VMCNT(2); } else { VMCNT(0); }
          int cc = dir ? 63 - ci : ci;
          int g = cc >> 5, kc = cc & 31;
          const u16* wb = wbW + (ci % 3) * 1024;
          bf16x8 aF = *(const bf16x8*)(bufA + swz8(col, kc * 32 + quad * 8));
          bf16x8 f0 = *(const bf16x8*)(wb + rslot * 8);
          bf16x8 f1 = *(const bf16x8*)(wb + 512 + rslot * 8);
          acc[g * 2 + 0] = __builtin_amdgcn_mfma_f32_16x16x32_bf16(aF, f0, acc[g * 2 + 0], 0, 0, 0);
          acc[g * 2 + 1] = __builtin_amdgcn_mfma_f32_16x16x32_bf16(aF, f1, acc[g * 2 + 1], 0, 0, 0);
        }
      }
#pragma unroll
      for (int t = 0; t < 4; t++) {
        int c = cw + t * 16 + col;
        float bv = b1[c];
#pragma unroll
        for (int rr = 0; rr < 4; rr++)
          bufH[swz(quad * 4 + rr, c)] = f2b(fmaxf(acc[t][rr] + bv, 0.f));
      }
      __syncthreads();
      // ================= GEMM2: z = bufH @ w2^T ============================
      f32x4 acc2[4] = {};
      {
        int c0 = dir ? 63 : 0, c1 = dir ? 62 : 1;
        ode_stage(w2, wbW, cw + (c0 >> 5) * 32, c0 & 31, scl, sqg);
        ode_stage(w2, wbW + 1024, cw + (c1 >> 5) * 32, c1 & 31, scl, sqg);
        for (int ci = 0; ci < 62; ci++) {
          VMCNT(2);
          int cc = dir ? 63 - ci : ci;
          int g = cc >> 5, kc = cc & 31;
          const u16* wb = wbW + (ci % 3) * 1024;
          bf16x8 aF = *(const bf16x8*)(bufH + swz8(col, kc * 32 + quad * 8));
          bf16x8 f0 = *(const bf16x8*)(wb + rslot * 8);
          bf16x8 f1 = *(const bf16x8*)(wb + 512 + rslot * 8);
          acc2[g * 2 + 0] = __builtin_amdgcn_mfma_f32_16x16x32_bf16(aF, f0, acc2[g * 2 + 0], 0, 0, 0);
          acc2[g * 2 + 1] = __builtin_amdgcn_mfma_f32_16x16x32_bf16(aF, f1, acc2[g * 2 + 1], 0, 0, 0);
          int cn = dir ? 63 - (ci + 2) : (ci + 2);
          ode_stage(w2, wbW + ((ci + 2) % 3) * 1024, cw + (cn >> 5) * 32, cn & 31, scl, sqg);
        }
#pragma unroll
        for (int ci = 62; ci < 64; ci++) {
          if (ci == 62) { VMCNT(2); } else { VMCNT(0); }
          int cc = dir ? 63 - ci : ci;
          int g = cc >> 5, kc = cc & 31;
          const u16* wb = wbW + (ci % 3) * 1024;
          bf16x8 aF = *(const bf16x8*)(bufH + swz8(col, kc * 32 + quad * 8));
          bf16x8 f0 = *(const bf16x8*)(wb + rslot * 8);
          bf16x8 f1 = *(const bf16x8*)(wb + 512 + rslot * 8);
          acc2[g * 2 + 0] = __builtin_amdgcn_mfma_f32_16x16x32_bf16(aF, f0, acc2[g * 2 + 0], 0, 0, 0);
          acc2[g * 2 + 1] = __builtin_amdgcn_mfma_f32_16x16x32_bf16(aF, f1, acc2[g * 2 + 1], 0, 0, 0);
        }
      }
      __syncthreads();  // all waves done reading bufH before overwrite
      // ---- z = acc2 + b2 + resid(bufA) -> bufH ----
#pragma unroll
      for (int t = 0; t < 4; t++) {
        int c = cw + t * 16 + col;
        float bv = b2[c];
#pragma unroll
        for (int rr = 0; rr < 4; rr++) {
          int mr = quad * 4 + rr;
          float z = acc2[t][rr] + bv + b2f(bufA[swz(mr, c)]);
          bufH[swz(mr, c)] = f2b(z);
        }
      }
      __syncthreads();
      // ---- epilogue: LN (wave = token) + RK4 state update ----
      {
        float z16[16];
        float s1 = 0.f, s2 = 0.f;
#pragma unroll
        for (int j = 0; j < 16; j++) {
          z16[j] = b2f(bufH[swz(wvid, ec0 + j)]);
          s1 += z16[j]; s2 += z16[j] * z16[j];
        }
        for (int off = 1; off < 64; off <<= 1) {
          s1 += __shfl_xor(s1, off); s2 += __shfl_xor(s2, off);
        }
        float mean = s1 * (1.f / 1024.f);
        float var = s2 * (1.f / 1024.f) - mean * mean;
        float rstd = rsqrtf(var + EPSF);
        float cf = (ph < 2) ? 0.5f * RESF : RESF;
#pragma unroll
        for (int j = 0; j < 16; j++) {
          int c = ec0 + j;
          float k = (z16[j] - mean) * rstd * ng[c] + nb[c];
          float nv;
          if (ph == 0)      { accr[j] = k;        nv = y[j] + cf * k; }
          else if (ph < 3)  { accr[j] += 2.f * k; nv = y[j] + cf * k; }
          else              { y[j] += h6 * (accr[j] + k); nv = y[j]; }
          bufA[swz(wvid, c)] = f2b(nv);
        }
        if (ph == 3 && (s + 1) == idxb) {
          float* op = out + (size_t)(m0 + wvid) * 1024 + ec0;
#pragma unroll
          for (int j = 0; j < 16; j++) op[j] = y[j];
        }
      }
      __syncthreads();
    }
  }
}

// ---------------------------------------------------------------------------
// Unpatchify: y3[m][p*10+q*5+c] -> out[b][c][hh*2+p][ww*2+q], FLOAT32
// ---------------------------------------------------------------------------
__global__ __launch_bounds__(256) void k_unpatch(
    const float* __restrict__ y3, float* __restrict__ outp) {
  int o = blockIdx.x * 256 + threadIdx.x;
  if (o >= 20480) return;
  int b = o / 10240;
  int c = (o / 2048) % 5;
  int hrow = (o / 64) % 32;
  int wcol = o % 64;
  int hh = hrow >> 1, p = hrow & 1, ww = wcol >> 1, q = wcol & 1;
  int m2 = b * 512 + hh * 32 + ww;
  int colj = p * 10 + q * 5 + c;
  outp[o] = y3[(size_t)m2 * 20 + colj];
}

// ===========================================================================
extern "C" void kernel_launch(void* const* d_in, const int* in_sizes, int n_in,
                              void* d_out, int out_size, void* d_ws, size_t ws_size,
                              hipStream_t stream) {
  const float* x         = (const float*)d_in[0];
  const float* lead      = (const float*)d_in[1];
  const float* patch_w   = (const float*)d_in[2];
  const float* patch_b   = (const float*)d_in[3];
  const float* var_embed = (const float*)d_in[4];
  const float* var_query = (const float*)d_in[5];
  const float* agg_in_w  = (const float*)d_in[6];
  const float* agg_in_b  = (const float*)d_in[7];
  const float* agg_out_w = (const float*)d_in[8];
  const float* agg_out_b = (const float*)d_in[9];
  const float* pos_embed = (const float*)d_in[10];
  const float* lt_w      = (const float*)d_in[11];
  const float* lt_b      = (const float*)d_in[12];
  const float* blk_qkv_w = (const float*)d_in[13];
  const float* blk_qkv_b = (const float*)d_in[14];
  const float* blk_out_w = (const float*)d_in[15];
  const float* blk_out_b = (const float*)d_in[16];
  const float* blk_n1_g  = (const float*)d_in[17];
  const float* blk_n1_b  = (const float*)d_in[18];
  const float* blk_n2_g  = (const float*)d_in[19];
  const float* blk_n2_b  = (const float*)d_in[20];
  const float* ode_w1    = (const float*)d_in[21];
  const float* ode_b1    = (const float*)d_in[22];
  const float* ode_w2    = (const float*)d_in[23];
  const float* ode_b2    = (const float*)d_in[24];
  const float* ode_ng    = (const float*)d_in[25];
  const float* ode_nb    = (const float*)d_in[26];
  const float* norm_g    = (const float*)d_in[27];
  const float* norm_b    = (const float*)d_in[28];
  const float* h1_w      = (const float*)d_in[29];
  const float* h1_b      = (const float*)d_in[30];
  const float* h2_w      = (const float*)d_in[31];
  const float* h2_b      = (const float*)d_in[32];
  const float* hf_w      = (const float*)d_in[33];
  const float* hf_b      = (const float*)d_in[34];
  (void)in_sizes; (void)n_in; (void)out_size; (void)ws_size;

  float* ws = (float*)d_ws;
  float* patches = ws + 0;         // 20480
  float* qvec    = ws + 20480;     // 1024
  float* qb      = ws + 21504;     // 256 (16 used)
  float* u       = ws + 21760;     // 16384
  float* PU      = ws + 38144;     // 320
  float* C0      = ws + 38464;     // 80 (pad to 40960)
  float* amat    = ws + 40960;     // 81920
  float* PW      = ws + 122880;    // 20480
  float* CV      = ws + 143360;    // 5120  (end 148480 < 3145728)
  float* agg     = ws + 3145728;   // 1048576 (attno slot; dead by then)
  float* qkv   = ws + 0;           // 3145728
  float* attno = ws + 3145728;     // 1048576
  float* t1    = ws + 4194304;     // 1048576
  float* odeo  = ws + 5242880;     // 1048576
  float* xs    = ws + 6291456;     // 1048576
  u16*   w16a  = (u16*)(ws + 7340032);  // per-depth w1 (bf16)
  u16*   w16b  = (u16*)(ws + 7864320);  // per-depth w2 (bf16)
  float* y1 = ws + 0;
  float* y2 = ws + 1048576;
  float* y3 = ws + 2097152;        // 20480

  // ---- stage 1 ----
  k_patches<<<dim3(80), dim3(256), 0, stream>>>(x, patches);
  k_qvec<<<dim3(64), dim3(256), 0, stream>>>(var_query, agg_in_w, agg_in_b, qvec);
  k_qb<<<dim3(1), dim3(256), 0, stream>>>(qvec, agg_in_b + 1024, qb);
  k_u<<<dim3(64), dim3(256), 0, stream>>>(qvec, agg_in_w + (size_t)1024 * 1024, u);
  k_pu<<<dim3(80), dim3(256), 0, stream>>>(patch_w, patch_b, var_embed, u, qb, PU, C0);
  k_pw<<<dim3(5120), dim3(256), 0, stream>>>(
      agg_in_w + (size_t)2048 * 1024, agg_in_b + 2048, patch_w, patch_b,
      var_embed, PW, CV);
  k_scoresm<<<dim3(1024), dim3(256), 0, stream>>>(patches, PU, C0, amat);
  k_agg<<<dim3(1024), dim3(256), 0, stream>>>(patches, PW, CV, amat, agg);
  k_gemm<3><<<dim3(16, 16), dim3(256), 0, stream>>>(
      agg, agg_out_w, agg_out_b, xs, 1024, 1024, 1024,
      nullptr, pos_embed, lt_w, lt_b, lead);

  // ---- transformer blocks ----
  for (int i = 0; i < 2; i++) {
    k_gemm<0><<<dim3(48, 16), dim3(256), 0, stream>>>(
        xs, blk_qkv_w + (size_t)i * 3072 * 1024, blk_qkv_b + i * 3072, qkv,
        1024, 3072, 1024, nullptr, nullptr, nullptr, nullptr, nullptr);
    k_attn<<<dim3(1024), dim3(256), 0, stream>>>(qkv, attno);
    k_gemm<2><<<dim3(16, 16), dim3(256), 0, stream>>>(
        attno, blk_out_w + (size_t)i * 1048576, blk_out_b + i * 1024, t1,
        1024, 1024, 1024, xs, nullptr, nullptr, nullptr, nullptr);
    k_ln<<<dim3(1024), dim3(256), 0, stream>>>(
        t1, (const float*)nullptr, blk_n1_g + i * 1024, blk_n1_b + i * 1024, xs);
    k_cvt<<<dim3(4096), dim3(256), 0, stream>>>(ode_w1 + (size_t)i * 1048576, w16a, 1048576);
    k_cvt<<<dim3(4096), dim3(256), 0, stream>>>(ode_w2 + (size_t)i * 1048576, w16b, 1048576);
    k_ode<<<dim3(64), dim3(1024), 0, stream>>>(
        xs, odeo, w16a, ode_b1 + i * 1024, w16b, ode_b2 + i * 1024,
        ode_ng + i * 1024, ode_nb + i * 1024, lead);
    k_ln<<<dim3(1024), dim3(256), 0, stream>>>(
        xs, odeo, blk_n2_g + i * 1024, blk_n2_b + i * 1024, xs);
  }

  // ---- head ----
  k_ln<<<dim3(1024), dim3(256), 0, stream>>>(
      xs, (const float*)nullptr, norm_g, norm_b, xs);
  k_gemm<1><<<dim3(16, 16), dim3(256), 0, stream>>>(
      xs, h1_w, h1_b, y1, 1024, 1024, 1024, nullptr, nullptr, nullptr, nullptr, nullptr);
  k_gemm<1><<<dim3(16, 16), dim3(256), 0, stream>>>(
      y1, h2_w, h2_b, y2, 1024, 1024, 1024, nullptr, nullptr, nullptr, nullptr, nullptr);
  k_gemm<0><<<dim3(1, 16), dim3(256), 0, stream>>>(
      y2, hf_w, hf_b, y3, 1024, 20, 1024, nullptr, nullptr, nullptr, nullptr, nullptr);
  k_unpatch<<<dim3(80), dim3(256), 0, stream>>>(y3, (float*)d_out);
}